// Round 2
// baseline (862.734 us; speedup 1.0000x reference)
//
#include <hip/hip_runtime.h>
#include <math.h>

// Problem constants
#define HW 4096          // 64*64 latent positions
#define C 320            // channels
#define CX 768           // encoder channels
#define L 77             // encoder seq len
#define NB 10            // batches after concat (1 uncond + 9 cond)
#define NH 8             // heads
#define HD 40            // head dim
#define NINST 8          // bboxes
#define SCALE 0.15811388300841898f  // 1/sqrt(40)

// ---------------------------------------------------------------------------
// Mask / phase-weight kernel (separable antialiased bilinear resize of the
// box indicator, matching jax.image.resize 512->64).
// ---------------------------------------------------------------------------
__device__ __forceinline__ float axis_profile(int o, float lo, float hi) {
    float num = 0.f, den = 0.f;
    int j0 = 8 * o - 4;
#pragma unroll
    for (int t = 0; t < 16; ++t) {
        int j = j0 + t;
        float wt = 1.0f - fabsf((float)t - 7.5f) * 0.125f;
        if (j >= 0 && j < 512) {
            den += wt;
            float fj = (float)j;
            if (fj >= lo && fj < hi) num += wt;
        }
    }
    return num / den;
}

__global__ void maskw_kernel(const float* __restrict__ bboxes,  // (8,4)
                             float* __restrict__ wPh,           // (9, HW)
                             float* __restrict__ wSum) {        // (HW)
    int hw = blockIdx.x * 256 + threadIdx.x;
    if (hw >= HW) return;
    int oy = hw >> 6, ox = hw & 63;
    float sum = 0.1f;
    wPh[hw] = 0.1f;
#pragma unroll
    for (int n = 0; n < NINST; ++n) {
        float x0 = bboxes[n * 4 + 0];
        float y0 = bboxes[n * 4 + 1];
        float x1 = bboxes[n * 4 + 2];
        float y1 = bboxes[n * 4 + 3];
        float w_min = floorf(512.f * x0);
        float h_min = floorf(512.f * y0);
        float w_max = floorf(512.f * x1);
        float h_max = floorf(512.f * y1);
        float sh = axis_profile(oy, h_min, h_max);
        float sw = axis_profile(ox, w_min, w_max);
        float wv = 10.f * sh * sw;
        wPh[(n + 1) * HW + hw] = wv;
        sum += wv;
    }
    wSum[hw] = sum;
}

// ---------------------------------------------------------------------------
// Generic fp32 tiled GEMM: C[M,N] = A[M,K] @ B[K,N] (unchanged this round)
// ---------------------------------------------------------------------------
#define TS 64
#define KT 16
#define LDP (TS + 4)

__global__ __launch_bounds__(256) void gemm_f32(const float* __restrict__ A,
                                                const float* __restrict__ B,
                                                float* __restrict__ Cm,
                                                int M, int N, int K) {
    __shared__ float As[KT][LDP];
    __shared__ float Bs[KT][LDP];
    int tid = threadIdx.x;
    int tx = tid & 15, ty = tid >> 4;
    int row0 = blockIdx.y * TS, col0 = blockIdx.x * TS;
    float acc[4][4] = {{0.f}};

    for (int k0 = 0; k0 < K; k0 += KT) {
        {
            int m = tid & 63;
            int kk = (tid >> 6) << 2;
            int gr = row0 + m;
            float4 a4 = make_float4(0.f, 0.f, 0.f, 0.f);
            if (gr < M) a4 = *(const float4*)(A + (size_t)gr * K + k0 + kk);
            As[kk + 0][m] = a4.x;
            As[kk + 1][m] = a4.y;
            As[kk + 2][m] = a4.z;
            As[kk + 3][m] = a4.w;
        }
        {
            int n = (tid & 15) << 2;
            int kk = tid >> 4;
            float4 b4 = *(const float4*)(B + (size_t)(k0 + kk) * N + col0 + n);
            *(float4*)&Bs[kk][n] = b4;
        }
        __syncthreads();
#pragma unroll
        for (int kk = 0; kk < KT; ++kk) {
            float4 a = *(const float4*)&As[kk][ty << 2];
            float4 b = *(const float4*)&Bs[kk][tx << 2];
            acc[0][0] = fmaf(a.x, b.x, acc[0][0]);
            acc[0][1] = fmaf(a.x, b.y, acc[0][1]);
            acc[0][2] = fmaf(a.x, b.z, acc[0][2]);
            acc[0][3] = fmaf(a.x, b.w, acc[0][3]);
            acc[1][0] = fmaf(a.y, b.x, acc[1][0]);
            acc[1][1] = fmaf(a.y, b.y, acc[1][1]);
            acc[1][2] = fmaf(a.y, b.z, acc[1][2]);
            acc[1][3] = fmaf(a.y, b.w, acc[1][3]);
            acc[2][0] = fmaf(a.z, b.x, acc[2][0]);
            acc[2][1] = fmaf(a.z, b.y, acc[2][1]);
            acc[2][2] = fmaf(a.z, b.z, acc[2][2]);
            acc[2][3] = fmaf(a.z, b.w, acc[2][3]);
            acc[3][0] = fmaf(a.w, b.x, acc[3][0]);
            acc[3][1] = fmaf(a.w, b.y, acc[3][1]);
            acc[3][2] = fmaf(a.w, b.z, acc[3][2]);
            acc[3][3] = fmaf(a.w, b.w, acc[3][3]);
        }
        __syncthreads();
    }
#pragma unroll
    for (int i = 0; i < 4; ++i) {
        int row = row0 + (ty << 2) + i;
        if (row < M) {
            float4 v = make_float4(acc[i][0], acc[i][1], acc[i][2], acc[i][3]);
            *(float4*)(Cm + (size_t)row * N + col0 + (tx << 2)) = v;
        }
    }
}

// ---------------------------------------------------------------------------
// O-projection GEMM with fused epilogue (unchanged this round)
// ---------------------------------------------------------------------------
__global__ __launch_bounds__(256) void gemm_oproj(const float* __restrict__ A,
                                                  const float* __restrict__ B,
                                                  const float* __restrict__ bo,
                                                  const float* __restrict__ wSum,
                                                  float* __restrict__ Out) {
    const int N = C, K = C;
    __shared__ float As[KT][LDP];
    __shared__ float Bs[KT][LDP];
    int tid = threadIdx.x;
    int tx = tid & 15, ty = tid >> 4;
    int row0 = blockIdx.y * TS, col0 = blockIdx.x * TS;
    float acc[4][4] = {{0.f}};

    for (int k0 = 0; k0 < K; k0 += KT) {
        {
            int m = tid & 63;
            int kk = (tid >> 6) << 2;
            int gr = row0 + m;
            float4 a4 = *(const float4*)(A + (size_t)gr * K + k0 + kk);
            As[kk + 0][m] = a4.x;
            As[kk + 1][m] = a4.y;
            As[kk + 2][m] = a4.z;
            As[kk + 3][m] = a4.w;
        }
        {
            int n = (tid & 15) << 2;
            int kk = tid >> 4;
            float4 b4 = *(const float4*)(B + (size_t)(k0 + kk) * N + col0 + n);
            *(float4*)&Bs[kk][n] = b4;
        }
        __syncthreads();
#pragma unroll
        for (int kk = 0; kk < KT; ++kk) {
            float4 a = *(const float4*)&As[kk][ty << 2];
            float4 b = *(const float4*)&Bs[kk][tx << 2];
            acc[0][0] = fmaf(a.x, b.x, acc[0][0]);
            acc[0][1] = fmaf(a.x, b.y, acc[0][1]);
            acc[0][2] = fmaf(a.x, b.z, acc[0][2]);
            acc[0][3] = fmaf(a.x, b.w, acc[0][3]);
            acc[1][0] = fmaf(a.y, b.x, acc[1][0]);
            acc[1][1] = fmaf(a.y, b.y, acc[1][1]);
            acc[1][2] = fmaf(a.y, b.z, acc[1][2]);
            acc[1][3] = fmaf(a.y, b.w, acc[1][3]);
            acc[2][0] = fmaf(a.z, b.x, acc[2][0]);
            acc[2][1] = fmaf(a.z, b.y, acc[2][1]);
            acc[2][2] = fmaf(a.z, b.z, acc[2][2]);
            acc[2][3] = fmaf(a.z, b.w, acc[2][3]);
            acc[3][0] = fmaf(a.w, b.x, acc[3][0]);
            acc[3][1] = fmaf(a.w, b.y, acc[3][1]);
            acc[3][2] = fmaf(a.w, b.z, acc[3][2]);
            acc[3][3] = fmaf(a.w, b.w, acc[3][3]);
        }
        __syncthreads();
    }

    int colb = col0 + (tx << 2);
    float4 bov = *(const float4*)(bo + colb);
#pragma unroll
    for (int i = 0; i < 4; ++i) {
        int row = row0 + (ty << 2) + i;
        float4 v = make_float4(acc[i][0], acc[i][1], acc[i][2], acc[i][3]);
        if (row < HW) {
            v.x += bov.x; v.y += bov.y; v.z += bov.z; v.w += bov.w;
        } else {
            float ws = wSum[row - HW];
            float rinv = 1.0f / (ws + 1e-6f);
            v.x = (v.x + bov.x * ws) * rinv;
            v.y = (v.y + bov.y * ws) * rinv;
            v.z = (v.z + bov.z * ws) * rinv;
            v.w = (v.w + bov.w * ws) * rinv;
        }
        *(float4*)(Out + (size_t)row * N + colb) = v;
    }
}

// ---------------------------------------------------------------------------
// Attention v2: one block per (batch, head, 256-query tile) -> 1280 uniform
// blocks, 128 threads, 2 queries/thread. K/V staged in LDS as float4;
// all inner reads are wave-broadcast (conflict-free). Cond batches (1..9)
// atomically add their phase-weighted contribution w_b/l * o into X rows
// 4096..8191 (zeroed beforehand); batch 0 writes rows 0..4095 directly.
// Logits ~N(0,0.2) -> exp without max-subtraction is safe in fp32.
// ---------------------------------------------------------------------------
__global__ __launch_bounds__(128) void attn_kernel(const float* __restrict__ Q,   // (8192,320)
                                                   const float* __restrict__ Kb,  // (770,320)
                                                   const float* __restrict__ Vb,  // (770,320)
                                                   const float* __restrict__ wPh, // (9,HW)
                                                   float* __restrict__ X) {       // (8192,320)
    __shared__ float4 ksv[L * 10];
    __shared__ float4 vsv[L * 10];
    int tid = threadIdx.x;
    int b    = blockIdx.x >> 7;        // 0..9
    int rest = blockIdx.x & 127;
    int head = rest >> 4;              // 0..7
    int tile = rest & 15;              // 0..15
    int row0 = tile * 256 + tid;       // 0..4095
    int row1 = row0 + 128;

    // stage K,V for this (batch, head)
    for (int idx = tid; idx < L * 10; idx += 128) {
        int j = idx / 10, r = idx - j * 10;
        const float4* kg4 = (const float4*)(Kb + (size_t)(b * L + j) * C + head * HD);
        const float4* vg4 = (const float4*)(Vb + (size_t)(b * L + j) * C + head * HD);
        ksv[idx] = kg4[r];
        vsv[idx] = vg4[r];
    }

    // load the two query rows
    int qbase = (b == 0) ? 0 : HW;
    const float4* qp0 = (const float4*)(Q + (size_t)(qbase + row0) * C + head * HD);
    const float4* qp1 = (const float4*)(Q + (size_t)(qbase + row1) * C + head * HD);
    float4 q0[10], q1[10];
#pragma unroll
    for (int i = 0; i < 10; ++i) { q0[i] = qp0[i]; q1[i] = qp1[i]; }

    __syncthreads();

    float l0 = 0.f, l1 = 0.f;
    float4 o0[10], o1[10];
#pragma unroll
    for (int i = 0; i < 10; ++i) {
        o0[i] = make_float4(0.f, 0.f, 0.f, 0.f);
        o1[i] = make_float4(0.f, 0.f, 0.f, 0.f);
    }

    for (int j = 0; j < L; ++j) {
        const float4* kj = &ksv[j * 10];
        float4 a0 = make_float4(0.f, 0.f, 0.f, 0.f);
        float4 a1 = make_float4(0.f, 0.f, 0.f, 0.f);
#pragma unroll
        for (int i = 0; i < 10; ++i) {
            float4 kk = kj[i];
            a0.x = fmaf(q0[i].x, kk.x, a0.x);
            a0.y = fmaf(q0[i].y, kk.y, a0.y);
            a0.z = fmaf(q0[i].z, kk.z, a0.z);
            a0.w = fmaf(q0[i].w, kk.w, a0.w);
            a1.x = fmaf(q1[i].x, kk.x, a1.x);
            a1.y = fmaf(q1[i].y, kk.y, a1.y);
            a1.z = fmaf(q1[i].z, kk.z, a1.z);
            a1.w = fmaf(q1[i].w, kk.w, a1.w);
        }
        float p0 = __expf(((a0.x + a0.y) + (a0.z + a0.w)) * SCALE);
        float p1 = __expf(((a1.x + a1.y) + (a1.z + a1.w)) * SCALE);
        l0 += p0;
        l1 += p1;
        const float4* vj = &vsv[j * 10];
#pragma unroll
        for (int i = 0; i < 10; ++i) {
            float4 vv = vj[i];
            o0[i].x = fmaf(p0, vv.x, o0[i].x);
            o0[i].y = fmaf(p0, vv.y, o0[i].y);
            o0[i].z = fmaf(p0, vv.z, o0[i].z);
            o0[i].w = fmaf(p0, vv.w, o0[i].w);
            o1[i].x = fmaf(p1, vv.x, o1[i].x);
            o1[i].y = fmaf(p1, vv.y, o1[i].y);
            o1[i].z = fmaf(p1, vv.z, o1[i].z);
            o1[i].w = fmaf(p1, vv.w, o1[i].w);
        }
    }

    if (b == 0) {
        float r0 = 1.0f / l0, r1 = 1.0f / l1;
        float4* xp0 = (float4*)(X + (size_t)row0 * C + head * HD);
        float4* xp1 = (float4*)(X + (size_t)row1 * C + head * HD);
#pragma unroll
        for (int i = 0; i < 10; ++i) {
            xp0[i] = make_float4(o0[i].x * r0, o0[i].y * r0, o0[i].z * r0, o0[i].w * r0);
            xp1[i] = make_float4(o1[i].x * r1, o1[i].y * r1, o1[i].z * r1, o1[i].w * r1);
        }
    } else {
        float w0 = wPh[(size_t)(b - 1) * HW + row0];
        float w1 = wPh[(size_t)(b - 1) * HW + row1];
        float r0 = w0 / l0, r1 = w1 / l1;
        float* xp0 = X + (size_t)(HW + row0) * C + head * HD;
        float* xp1 = X + (size_t)(HW + row1) * C + head * HD;
        const float* f0 = (const float*)o0;
        const float* f1 = (const float*)o1;
#pragma unroll
        for (int d = 0; d < HD; ++d) {
            unsafeAtomicAdd(xp0 + d, r0 * f0[d]);
            unsafeAtomicAdd(xp1 + d, r1 * f1[d]);
        }
    }
}

// ---------------------------------------------------------------------------
// Launch
// ---------------------------------------------------------------------------
extern "C" void kernel_launch(void* const* d_in, const int* in_sizes, int n_in,
                              void* d_out, int out_size, void* d_ws, size_t ws_size,
                              hipStream_t stream) {
    const float* hs   = (const float*)d_in[0];
    const float* ehs  = (const float*)d_in[1];
    const float* bbox = (const float*)d_in[2];
    const float* Wq   = (const float*)d_in[3];
    const float* Wk   = (const float*)d_in[4];
    const float* Wv   = (const float*)d_in[5];
    const float* Wo   = (const float*)d_in[6];
    const float* bo   = (const float*)d_in[7];
    float* out = (float*)d_out;

    float* Qbuf = (float*)d_ws;                 // 8192*320
    float* Kbuf = Qbuf + (size_t)2 * HW * C;    // 770*320
    float* Vbuf = Kbuf + (size_t)NB * L * C;    // 770*320
    float* Xbuf = Vbuf + (size_t)NB * L * C;    // 8192*320
    float* wPh  = Xbuf + (size_t)2 * HW * C;    // 9*4096
    float* wSum = wPh + (size_t)(NINST + 1) * HW;

    maskw_kernel<<<dim3(HW / 256), 256, 0, stream>>>(bbox, wPh, wSum);
    gemm_f32<<<dim3(C / TS, (2 * HW) / TS), 256, 0, stream>>>(hs, Wq, Qbuf, 2 * HW, C, C);
    gemm_f32<<<dim3(C / TS, (NB * L + TS - 1) / TS), 256, 0, stream>>>(ehs, Wk, Kbuf, NB * L, C, CX);
    gemm_f32<<<dim3(C / TS, (NB * L + TS - 1) / TS), 256, 0, stream>>>(ehs, Wv, Vbuf, NB * L, C, CX);
    // zero the cond half of X (atomic accumulation target)
    hipMemsetAsync((void*)(Xbuf + (size_t)HW * C), 0, (size_t)HW * C * sizeof(float), stream);
    attn_kernel<<<dim3(NB * NH * 16), 128, 0, stream>>>(Qbuf, Kbuf, Vbuf, wPh, Xbuf);
    gemm_oproj<<<dim3(C / TS, (2 * HW) / TS), 256, 0, stream>>>(Xbuf, Wo, bo, wSum, out);
}

// Round 3
// 315.870 us; speedup vs baseline: 2.7313x; 2.7313x over previous
//
#include <hip/hip_runtime.h>
#include <math.h>

// Problem constants
#define HW 4096          // 64*64 latent positions
#define C 320            // channels
#define CX 768           // encoder channels
#define L 77             // encoder seq len
#define NB 10            // batches after concat (1 uncond + 9 cond)
#define NH 8             // heads
#define HD 40            // head dim
#define NINST 8          // bboxes
#define SCALE 0.15811388300841898f  // 1/sqrt(40)

// ---------------------------------------------------------------------------
// Mask / phase-weight kernel (separable antialiased bilinear resize of the
// box indicator, matching jax.image.resize 512->64).
// ---------------------------------------------------------------------------
__device__ __forceinline__ float axis_profile(int o, float lo, float hi) {
    float num = 0.f, den = 0.f;
    int j0 = 8 * o - 4;
#pragma unroll
    for (int t = 0; t < 16; ++t) {
        int j = j0 + t;
        float wt = 1.0f - fabsf((float)t - 7.5f) * 0.125f;
        if (j >= 0 && j < 512) {
            den += wt;
            float fj = (float)j;
            if (fj >= lo && fj < hi) num += wt;
        }
    }
    return num / den;
}

__global__ void maskw_kernel(const float* __restrict__ bboxes,  // (8,4)
                             float* __restrict__ wPh,           // (9, HW)
                             float* __restrict__ wSum) {        // (HW)
    int hw = blockIdx.x * 256 + threadIdx.x;
    if (hw >= HW) return;
    int oy = hw >> 6, ox = hw & 63;
    float sum = 0.1f;
    wPh[hw] = 0.1f;
#pragma unroll
    for (int n = 0; n < NINST; ++n) {
        float x0 = bboxes[n * 4 + 0];
        float y0 = bboxes[n * 4 + 1];
        float x1 = bboxes[n * 4 + 2];
        float y1 = bboxes[n * 4 + 3];
        float w_min = floorf(512.f * x0);
        float h_min = floorf(512.f * y0);
        float w_max = floorf(512.f * x1);
        float h_max = floorf(512.f * y1);
        float sh = axis_profile(oy, h_min, h_max);
        float sw = axis_profile(ox, w_min, w_max);
        float wv = 10.f * sh * sw;
        wPh[(n + 1) * HW + hw] = wv;
        sum += wv;
    }
    wSum[hw] = sum;
}

// ---------------------------------------------------------------------------
// Generic fp32 tiled GEMM: C[M,N] = A[M,K] @ B[K,N]
// ---------------------------------------------------------------------------
#define TS 64
#define KT 16
#define LDP (TS + 4)

__global__ __launch_bounds__(256) void gemm_f32(const float* __restrict__ A,
                                                const float* __restrict__ B,
                                                float* __restrict__ Cm,
                                                int M, int N, int K) {
    __shared__ float As[KT][LDP];
    __shared__ float Bs[KT][LDP];
    int tid = threadIdx.x;
    int tx = tid & 15, ty = tid >> 4;
    int row0 = blockIdx.y * TS, col0 = blockIdx.x * TS;
    float acc[4][4] = {{0.f}};

    for (int k0 = 0; k0 < K; k0 += KT) {
        {
            int m = tid & 63;
            int kk = (tid >> 6) << 2;
            int gr = row0 + m;
            float4 a4 = make_float4(0.f, 0.f, 0.f, 0.f);
            if (gr < M) a4 = *(const float4*)(A + (size_t)gr * K + k0 + kk);
            As[kk + 0][m] = a4.x;
            As[kk + 1][m] = a4.y;
            As[kk + 2][m] = a4.z;
            As[kk + 3][m] = a4.w;
        }
        {
            int n = (tid & 15) << 2;
            int kk = tid >> 4;
            float4 b4 = *(const float4*)(B + (size_t)(k0 + kk) * N + col0 + n);
            *(float4*)&Bs[kk][n] = b4;
        }
        __syncthreads();
#pragma unroll
        for (int kk = 0; kk < KT; ++kk) {
            float4 a = *(const float4*)&As[kk][ty << 2];
            float4 b = *(const float4*)&Bs[kk][tx << 2];
            acc[0][0] = fmaf(a.x, b.x, acc[0][0]);
            acc[0][1] = fmaf(a.x, b.y, acc[0][1]);
            acc[0][2] = fmaf(a.x, b.z, acc[0][2]);
            acc[0][3] = fmaf(a.x, b.w, acc[0][3]);
            acc[1][0] = fmaf(a.y, b.x, acc[1][0]);
            acc[1][1] = fmaf(a.y, b.y, acc[1][1]);
            acc[1][2] = fmaf(a.y, b.z, acc[1][2]);
            acc[1][3] = fmaf(a.y, b.w, acc[1][3]);
            acc[2][0] = fmaf(a.z, b.x, acc[2][0]);
            acc[2][1] = fmaf(a.z, b.y, acc[2][1]);
            acc[2][2] = fmaf(a.z, b.z, acc[2][2]);
            acc[2][3] = fmaf(a.z, b.w, acc[2][3]);
            acc[3][0] = fmaf(a.w, b.x, acc[3][0]);
            acc[3][1] = fmaf(a.w, b.y, acc[3][1]);
            acc[3][2] = fmaf(a.w, b.z, acc[3][2]);
            acc[3][3] = fmaf(a.w, b.w, acc[3][3]);
        }
        __syncthreads();
    }
#pragma unroll
    for (int i = 0; i < 4; ++i) {
        int row = row0 + (ty << 2) + i;
        if (row < M) {
            float4 v = make_float4(acc[i][0], acc[i][1], acc[i][2], acc[i][3]);
            *(float4*)(Cm + (size_t)row * N + col0 + (tx << 2)) = v;
        }
    }
}

// ---------------------------------------------------------------------------
// O-projection GEMM with fused epilogue
// ---------------------------------------------------------------------------
__global__ __launch_bounds__(256) void gemm_oproj(const float* __restrict__ A,
                                                  const float* __restrict__ B,
                                                  const float* __restrict__ bo,
                                                  const float* __restrict__ wSum,
                                                  float* __restrict__ Out) {
    const int N = C, K = C;
    __shared__ float As[KT][LDP];
    __shared__ float Bs[KT][LDP];
    int tid = threadIdx.x;
    int tx = tid & 15, ty = tid >> 4;
    int row0 = blockIdx.y * TS, col0 = blockIdx.x * TS;
    float acc[4][4] = {{0.f}};

    for (int k0 = 0; k0 < K; k0 += KT) {
        {
            int m = tid & 63;
            int kk = (tid >> 6) << 2;
            int gr = row0 + m;
            float4 a4 = *(const float4*)(A + (size_t)gr * K + k0 + kk);
            As[kk + 0][m] = a4.x;
            As[kk + 1][m] = a4.y;
            As[kk + 2][m] = a4.z;
            As[kk + 3][m] = a4.w;
        }
        {
            int n = (tid & 15) << 2;
            int kk = tid >> 4;
            float4 b4 = *(const float4*)(B + (size_t)(k0 + kk) * N + col0 + n);
            *(float4*)&Bs[kk][n] = b4;
        }
        __syncthreads();
#pragma unroll
        for (int kk = 0; kk < KT; ++kk) {
            float4 a = *(const float4*)&As[kk][ty << 2];
            float4 b = *(const float4*)&Bs[kk][tx << 2];
            acc[0][0] = fmaf(a.x, b.x, acc[0][0]);
            acc[0][1] = fmaf(a.x, b.y, acc[0][1]);
            acc[0][2] = fmaf(a.x, b.z, acc[0][2]);
            acc[0][3] = fmaf(a.x, b.w, acc[0][3]);
            acc[1][0] = fmaf(a.y, b.x, acc[1][0]);
            acc[1][1] = fmaf(a.y, b.y, acc[1][1]);
            acc[1][2] = fmaf(a.y, b.z, acc[1][2]);
            acc[1][3] = fmaf(a.y, b.w, acc[1][3]);
            acc[2][0] = fmaf(a.z, b.x, acc[2][0]);
            acc[2][1] = fmaf(a.z, b.y, acc[2][1]);
            acc[2][2] = fmaf(a.z, b.z, acc[2][2]);
            acc[2][3] = fmaf(a.z, b.w, acc[2][3]);
            acc[3][0] = fmaf(a.w, b.x, acc[3][0]);
            acc[3][1] = fmaf(a.w, b.y, acc[3][1]);
            acc[3][2] = fmaf(a.w, b.z, acc[3][2]);
            acc[3][3] = fmaf(a.w, b.w, acc[3][3]);
        }
        __syncthreads();
    }

    int colb = col0 + (tx << 2);
    float4 bov = *(const float4*)(bo + colb);
#pragma unroll
    for (int i = 0; i < 4; ++i) {
        int row = row0 + (ty << 2) + i;
        float4 v = make_float4(acc[i][0], acc[i][1], acc[i][2], acc[i][3]);
        if (row < HW) {
            v.x += bov.x; v.y += bov.y; v.z += bov.z; v.w += bov.w;
        } else {
            float ws = wSum[row - HW];
            float rinv = 1.0f / (ws + 1e-6f);
            v.x = (v.x + bov.x * ws) * rinv;
            v.y = (v.y + bov.y * ws) * rinv;
            v.z = (v.z + bov.z * ws) * rinv;
            v.w = (v.w + bov.w * ws) * rinv;
        }
        *(float4*)(Out + (size_t)row * N + colb) = v;
    }
}

// ---------------------------------------------------------------------------
// Attention v3: one block per (batch, head, 256-query tile) -> 1280 uniform
// blocks, 128 threads, 2 queries/thread. K/V staged in LDS as float4 with
// broadcast (conflict-free) reads. Batch 0 writes 1/l * o to X rows 0..4095.
// Cond batches write w_b/l * o with PLAIN float4 stores into a private slot
// Xall[b-1] (no atomics -> no RMW write-through; round-2 counter evidence:
// atomics caused 373 MB WRITE_SIZE and made the kernel HBM-write-bound).
// A separate reduce kernel sums the 9 slots.
// ---------------------------------------------------------------------------
__global__ __launch_bounds__(128) void attn_kernel(const float* __restrict__ Q,    // (8192,320)
                                                   const float* __restrict__ Kb,   // (770,320)
                                                   const float* __restrict__ Vb,   // (770,320)
                                                   const float* __restrict__ wPh,  // (9,HW)
                                                   float* __restrict__ X,          // (8192,320)
                                                   float* __restrict__ Xall) {     // (9,HW,320)
    __shared__ float4 ksv[L * 10];
    __shared__ float4 vsv[L * 10];
    int tid = threadIdx.x;
    int b    = blockIdx.x >> 7;        // 0..9
    int rest = blockIdx.x & 127;
    int head = rest >> 4;              // 0..7
    int tile = rest & 15;              // 0..15
    int row0 = tile * 256 + tid;       // 0..4095
    int row1 = row0 + 128;

    // stage K,V for this (batch, head)
    for (int idx = tid; idx < L * 10; idx += 128) {
        int j = idx / 10, r = idx - j * 10;
        const float4* kg4 = (const float4*)(Kb + (size_t)(b * L + j) * C + head * HD);
        const float4* vg4 = (const float4*)(Vb + (size_t)(b * L + j) * C + head * HD);
        ksv[idx] = kg4[r];
        vsv[idx] = vg4[r];
    }

    int qbase = (b == 0) ? 0 : HW;
    const float4* qp0 = (const float4*)(Q + (size_t)(qbase + row0) * C + head * HD);
    const float4* qp1 = (const float4*)(Q + (size_t)(qbase + row1) * C + head * HD);
    float4 q0[10], q1[10];
#pragma unroll
    for (int i = 0; i < 10; ++i) { q0[i] = qp0[i]; q1[i] = qp1[i]; }

    __syncthreads();

    float l0 = 0.f, l1 = 0.f;
    float4 o0[10], o1[10];
#pragma unroll
    for (int i = 0; i < 10; ++i) {
        o0[i] = make_float4(0.f, 0.f, 0.f, 0.f);
        o1[i] = make_float4(0.f, 0.f, 0.f, 0.f);
    }

    for (int j = 0; j < L; ++j) {
        const float4* kj = &ksv[j * 10];
        float4 a0 = make_float4(0.f, 0.f, 0.f, 0.f);
        float4 a1 = make_float4(0.f, 0.f, 0.f, 0.f);
#pragma unroll
        for (int i = 0; i < 10; ++i) {
            float4 kk = kj[i];
            a0.x = fmaf(q0[i].x, kk.x, a0.x);
            a0.y = fmaf(q0[i].y, kk.y, a0.y);
            a0.z = fmaf(q0[i].z, kk.z, a0.z);
            a0.w = fmaf(q0[i].w, kk.w, a0.w);
            a1.x = fmaf(q1[i].x, kk.x, a1.x);
            a1.y = fmaf(q1[i].y, kk.y, a1.y);
            a1.z = fmaf(q1[i].z, kk.z, a1.z);
            a1.w = fmaf(q1[i].w, kk.w, a1.w);
        }
        float p0 = __expf(((a0.x + a0.y) + (a0.z + a0.w)) * SCALE);
        float p1 = __expf(((a1.x + a1.y) + (a1.z + a1.w)) * SCALE);
        l0 += p0;
        l1 += p1;
        const float4* vj = &vsv[j * 10];
#pragma unroll
        for (int i = 0; i < 10; ++i) {
            float4 vv = vj[i];
            o0[i].x = fmaf(p0, vv.x, o0[i].x);
            o0[i].y = fmaf(p0, vv.y, o0[i].y);
            o0[i].z = fmaf(p0, vv.z, o0[i].z);
            o0[i].w = fmaf(p0, vv.w, o0[i].w);
            o1[i].x = fmaf(p1, vv.x, o1[i].x);
            o1[i].y = fmaf(p1, vv.y, o1[i].y);
            o1[i].z = fmaf(p1, vv.z, o1[i].z);
            o1[i].w = fmaf(p1, vv.w, o1[i].w);
        }
    }

    if (b == 0) {
        float r0 = 1.0f / l0, r1 = 1.0f / l1;
        float4* xp0 = (float4*)(X + (size_t)row0 * C + head * HD);
        float4* xp1 = (float4*)(X + (size_t)row1 * C + head * HD);
#pragma unroll
        for (int i = 0; i < 10; ++i) {
            xp0[i] = make_float4(o0[i].x * r0, o0[i].y * r0, o0[i].z * r0, o0[i].w * r0);
            xp1[i] = make_float4(o1[i].x * r1, o1[i].y * r1, o1[i].z * r1, o1[i].w * r1);
        }
    } else {
        float w0 = wPh[(size_t)(b - 1) * HW + row0];
        float w1 = wPh[(size_t)(b - 1) * HW + row1];
        float r0 = w0 / l0, r1 = w1 / l1;
        float4* xp0 = (float4*)(Xall + ((size_t)(b - 1) * HW + row0) * C + head * HD);
        float4* xp1 = (float4*)(Xall + ((size_t)(b - 1) * HW + row1) * C + head * HD);
#pragma unroll
        for (int i = 0; i < 10; ++i) {
            xp0[i] = make_float4(o0[i].x * r0, o0[i].y * r0, o0[i].z * r0, o0[i].w * r0);
            xp1[i] = make_float4(o1[i].x * r1, o1[i].y * r1, o1[i].z * r1, o1[i].w * r1);
        }
    }
}

// ---------------------------------------------------------------------------
// Reduce the 9 per-batch contributions into X rows 4096..8191.
// Memory-bound: 47 MB read + 5 MB write.
// ---------------------------------------------------------------------------
__global__ __launch_bounds__(256) void reduce_kernel(const float* __restrict__ Xall, // (9,HW,320)
                                                     float* __restrict__ X) {        // (8192,320)
    size_t idx = ((size_t)blockIdx.x * 256 + threadIdx.x) * 4;  // float4 index over HW*C
    const size_t slot = (size_t)HW * C;
    float4 s = *(const float4*)(Xall + idx);
#pragma unroll
    for (int b = 1; b < 9; ++b) {
        float4 v = *(const float4*)(Xall + (size_t)b * slot + idx);
        s.x += v.x; s.y += v.y; s.z += v.z; s.w += v.w;
    }
    *(float4*)(X + slot + idx) = s;
}

// ---------------------------------------------------------------------------
// Launch
// ---------------------------------------------------------------------------
extern "C" void kernel_launch(void* const* d_in, const int* in_sizes, int n_in,
                              void* d_out, int out_size, void* d_ws, size_t ws_size,
                              hipStream_t stream) {
    const float* hs   = (const float*)d_in[0];
    const float* ehs  = (const float*)d_in[1];
    const float* bbox = (const float*)d_in[2];
    const float* Wq   = (const float*)d_in[3];
    const float* Wk   = (const float*)d_in[4];
    const float* Wv   = (const float*)d_in[5];
    const float* Wo   = (const float*)d_in[6];
    const float* bo   = (const float*)d_in[7];
    float* out = (float*)d_out;

    float* Qbuf = (float*)d_ws;                       // 8192*320
    float* Kbuf = Qbuf + (size_t)2 * HW * C;          // 770*320
    float* Vbuf = Kbuf + (size_t)NB * L * C;          // 770*320
    float* Xbuf = Vbuf + (size_t)NB * L * C;          // 8192*320
    float* wPh  = Xbuf + (size_t)2 * HW * C;          // 9*4096
    float* wSum = wPh + (size_t)(NINST + 1) * HW;     // 4096
    float* Xall = wSum + (size_t)HW;                  // 9*4096*320

    maskw_kernel<<<dim3(HW / 256), 256, 0, stream>>>(bbox, wPh, wSum);
    gemm_f32<<<dim3(C / TS, (2 * HW) / TS), 256, 0, stream>>>(hs, Wq, Qbuf, 2 * HW, C, C);
    gemm_f32<<<dim3(C / TS, (NB * L + TS - 1) / TS), 256, 0, stream>>>(ehs, Wk, Kbuf, NB * L, C, CX);
    gemm_f32<<<dim3(C / TS, (NB * L + TS - 1) / TS), 256, 0, stream>>>(ehs, Wv, Vbuf, NB * L, C, CX);
    attn_kernel<<<dim3(NB * NH * 16), 128, 0, stream>>>(Qbuf, Kbuf, Vbuf, wPh, Xbuf, Xall);
    reduce_kernel<<<dim3((HW * C / 4) / 256), 256, 0, stream>>>(Xall, Xbuf);
    gemm_oproj<<<dim3(C / TS, (2 * HW) / TS), 256, 0, stream>>>(Xbuf, Wo, bo, wSum, out);
}

// Round 4
// 231.401 us; speedup vs baseline: 3.7283x; 1.3650x over previous
//
#include <hip/hip_runtime.h>
#include <math.h>

// Problem constants
#define HW 4096
#define C 320
#define CX 768
#define L 77
#define NB 10
#define NH 8
#define HD 40
#define NINST 8
#define KVC 640          // combined K|V column count
#define SCALE 0.15811388300841898f  // 1/sqrt(40)

typedef _Float16 half8v __attribute__((ext_vector_type(8)));
typedef _Float16 half4v __attribute__((ext_vector_type(4)));
typedef float f32x4 __attribute__((ext_vector_type(4)));

// ---------------------------------------------------------------------------
// Mask / phase-weight kernel (separable antialiased bilinear resize of the
// box indicator, matching jax.image.resize 512->64).
// ---------------------------------------------------------------------------
__device__ __forceinline__ float axis_profile(int o, float lo, float hi) {
    float num = 0.f, den = 0.f;
    int j0 = 8 * o - 4;
#pragma unroll
    for (int t = 0; t < 16; ++t) {
        int j = j0 + t;
        float wt = 1.0f - fabsf((float)t - 7.5f) * 0.125f;
        if (j >= 0 && j < 512) {
            den += wt;
            float fj = (float)j;
            if (fj >= lo && fj < hi) num += wt;
        }
    }
    return num / den;
}

__global__ void maskw_kernel(const float* __restrict__ bboxes,
                             float* __restrict__ wPh,
                             float* __restrict__ wSum) {
    int hw = blockIdx.x * 256 + threadIdx.x;
    if (hw >= HW) return;
    int oy = hw >> 6, ox = hw & 63;
    float sum = 0.1f;
    wPh[hw] = 0.1f;
#pragma unroll
    for (int n = 0; n < NINST; ++n) {
        float x0 = bboxes[n * 4 + 0];
        float y0 = bboxes[n * 4 + 1];
        float x1 = bboxes[n * 4 + 2];
        float y1 = bboxes[n * 4 + 3];
        float w_min = floorf(512.f * x0);
        float h_min = floorf(512.f * y0);
        float w_max = floorf(512.f * x1);
        float h_max = floorf(512.f * y1);
        float sh = axis_profile(oy, h_min, h_max);
        float sw = axis_profile(ox, w_min, w_max);
        float wv = 10.f * sh * sw;
        wPh[(n + 1) * HW + hw] = wv;
        sum += wv;
    }
    wSum[hw] = sum;
}

// ---------------------------------------------------------------------------
// fp32 -> f16 convert (vectorized, n4 = element count / 4)
// ---------------------------------------------------------------------------
__global__ __launch_bounds__(256) void cvt_f16(const float* __restrict__ src,
                                               _Float16* __restrict__ dst, int n4) {
    int i = blockIdx.x * 256 + threadIdx.x;
    if (i >= n4) return;
    float4 v = ((const float4*)src)[i];
    half4v h = {(_Float16)v.x, (_Float16)v.y, (_Float16)v.z, (_Float16)v.w};
    ((half4v*)dst)[i] = h;
}

// ---------------------------------------------------------------------------
// Weight transpose+pack: W (K x N, fp32, row-major) -> WT (N x K, f16).
// LDS tile transpose keeps both sides coalesced. Dims multiples of 64.
// ---------------------------------------------------------------------------
__global__ __launch_bounds__(256) void wpackT(const float* __restrict__ W,
                                              _Float16* __restrict__ WT,
                                              int K, int N) {
    __shared__ float tile[64][65];
    int nt = blockIdx.x * 64, kt = blockIdx.y * 64;
#pragma unroll
    for (int p = 0; p < 16; ++p) {
        int idx = p * 256 + threadIdx.x;
        int k = idx >> 6, n = idx & 63;
        tile[k][n] = W[(size_t)(kt + k) * N + nt + n];
    }
    __syncthreads();
#pragma unroll
    for (int p = 0; p < 16; ++p) {
        int idx = p * 256 + threadIdx.x;
        int n = idx >> 6, k = idx & 63;
        WT[(size_t)(nt + n) * K + kt + k] = (_Float16)tile[k][n];
    }
}

// ---------------------------------------------------------------------------
// f16 MFMA GEMM: C(M,N) fp32 = A(M,K) f16 @ BT(N,K) f16.
// 64x64 tile, 4 waves; wave w computes rows w*16..w*16+15 x 64 cols via
// 4x v_mfma_f32_16x16x32_f16. No LDS: A/B frags are contiguous 16B global
// loads (A row-major, B from W^T rows); weights are L2-resident.
// Fragment layouts (verified gfx950): A[m=lane&15][k=(lane>>4)*8+j],
// B[n=lane&15][k=(lane>>4)*8+j] (from B^T), C/D col=lane&15,row=(lane>>4)*4+r.
// ---------------------------------------------------------------------------
__global__ __launch_bounds__(256) void gemm_f16(const _Float16* __restrict__ A,
                                                const _Float16* __restrict__ BT,
                                                float* __restrict__ Cm,
                                                int M, int N, int K) {
    int lane = threadIdx.x & 63;
    int wave = threadIdx.x >> 6;
    int m0 = blockIdx.y * 64 + wave * 16;
    int n0 = blockIdx.x * 64;
    int lr = lane & 15;
    int kq = (lane >> 4) * 8;
    int arow = m0 + lr; if (arow >= M) arow = M - 1;   // clamp; stores guarded
    const _Float16* ap = A + (size_t)arow * K + kq;
    const _Float16* bp = BT + (size_t)(n0 + lr) * K + kq;
    f32x4 acc0 = {0.f,0.f,0.f,0.f}, acc1 = acc0, acc2 = acc0, acc3 = acc0;
    for (int k0 = 0; k0 < K; k0 += 32) {
        half8v af = *(const half8v*)(ap + k0);
        half8v b0 = *(const half8v*)(bp + k0);
        half8v b1 = *(const half8v*)(bp + (size_t)16 * K + k0);
        half8v b2 = *(const half8v*)(bp + (size_t)32 * K + k0);
        half8v b3 = *(const half8v*)(bp + (size_t)48 * K + k0);
        acc0 = __builtin_amdgcn_mfma_f32_16x16x32_f16(af, b0, acc0, 0, 0, 0);
        acc1 = __builtin_amdgcn_mfma_f32_16x16x32_f16(af, b1, acc1, 0, 0, 0);
        acc2 = __builtin_amdgcn_mfma_f32_16x16x32_f16(af, b2, acc2, 0, 0, 0);
        acc3 = __builtin_amdgcn_mfma_f32_16x16x32_f16(af, b3, acc3, 0, 0, 0);
    }
    int rb = m0 + ((lane >> 4) << 2);
    f32x4 accs[4] = {acc0, acc1, acc2, acc3};
#pragma unroll
    for (int t = 0; t < 4; ++t) {
        int col = n0 + t * 16 + lr;
#pragma unroll
        for (int r = 0; r < 4; ++r) {
            int row = rb + r;
            if (row < M) Cm[(size_t)row * N + col] = accs[t][r];
        }
    }
}

// ---------------------------------------------------------------------------
// O-projection f16 MFMA GEMM with fused epilogue. M=8192, N=K=320.
//   rows 0..4095   : out = v + bo[c]
//   rows 4096..8191: out = (v + bo[c]*wSum[hw]) / (wSum[hw] + 1e-6)
// ---------------------------------------------------------------------------
__global__ __launch_bounds__(256) void gemm_oproj_f16(const _Float16* __restrict__ A,
                                                      const _Float16* __restrict__ BT,
                                                      const float* __restrict__ bo,
                                                      const float* __restrict__ wSum,
                                                      float* __restrict__ Out) {
    const int K = C;
    int lane = threadIdx.x & 63;
    int wave = threadIdx.x >> 6;
    int m0 = blockIdx.y * 64 + wave * 16;
    int n0 = blockIdx.x * 64;
    int lr = lane & 15;
    int kq = (lane >> 4) * 8;
    const _Float16* ap = A + (size_t)(m0 + lr) * K + kq;
    const _Float16* bp = BT + (size_t)(n0 + lr) * K + kq;
    f32x4 acc0 = {0.f,0.f,0.f,0.f}, acc1 = acc0, acc2 = acc0, acc3 = acc0;
    for (int k0 = 0; k0 < K; k0 += 32) {
        half8v af = *(const half8v*)(ap + k0);
        half8v b0 = *(const half8v*)(bp + k0);
        half8v b1 = *(const half8v*)(bp + (size_t)16 * K + k0);
        half8v b2 = *(const half8v*)(bp + (size_t)32 * K + k0);
        half8v b3 = *(const half8v*)(bp + (size_t)48 * K + k0);
        acc0 = __builtin_amdgcn_mfma_f32_16x16x32_f16(af, b0, acc0, 0, 0, 0);
        acc1 = __builtin_amdgcn_mfma_f32_16x16x32_f16(af, b1, acc1, 0, 0, 0);
        acc2 = __builtin_amdgcn_mfma_f32_16x16x32_f16(af, b2, acc2, 0, 0, 0);
        acc3 = __builtin_amdgcn_mfma_f32_16x16x32_f16(af, b3, acc3, 0, 0, 0);
    }
    int rb = m0 + ((lane >> 4) << 2);
    f32x4 accs[4] = {acc0, acc1, acc2, acc3};
#pragma unroll
    for (int t = 0; t < 4; ++t) {
        int col = n0 + t * 16 + lr;
        float bv = bo[col];
#pragma unroll
        for (int r = 0; r < 4; ++r) {
            int row = rb + r;
            float v = accs[t][r];
            if (row < HW) {
                v += bv;
            } else {
                float ws = wSum[row - HW];
                v = (v + bv * ws) / (ws + 1e-6f);
            }
            Out[(size_t)row * C + col] = v;
        }
    }
}

// ---------------------------------------------------------------------------
// Attention: one block per (batch, head, 256-query tile) -> 1280 blocks,
// 128 threads, 2 queries/thread. K/V staged in LDS (broadcast reads).
// Batch 0 -> Xh rows 0..4095 (f16). Cond batches -> private f16 slot
// Xall[b-1] (plain stores; atomics proved HBM-write-bound in round 2).
// ---------------------------------------------------------------------------
__global__ __launch_bounds__(128) void attn_kernel(const float* __restrict__ Q,    // (8192,320) fp32
                                                   const float* __restrict__ KV,   // (770,640) fp32
                                                   const float* __restrict__ wPh,  // (9,HW)
                                                   _Float16* __restrict__ Xh,      // (8192,320) f16
                                                   _Float16* __restrict__ Xall) {  // (9,HW,320) f16
    __shared__ float4 ksv[L * 10];
    __shared__ float4 vsv[L * 10];
    int tid = threadIdx.x;
    int b    = blockIdx.x >> 7;
    int rest = blockIdx.x & 127;
    int head = rest >> 4;
    int tile = rest & 15;
    int row0 = tile * 256 + tid;
    int row1 = row0 + 128;

    for (int idx = tid; idx < L * 10; idx += 128) {
        int j = idx / 10, r = idx - j * 10;
        const float4* kg4 = (const float4*)(KV + (size_t)(b * L + j) * KVC + head * HD);
        const float4* vg4 = (const float4*)(KV + (size_t)(b * L + j) * KVC + C + head * HD);
        ksv[idx] = kg4[r];
        vsv[idx] = vg4[r];
    }

    int qbase = (b == 0) ? 0 : HW;
    const float4* qp0 = (const float4*)(Q + (size_t)(qbase + row0) * C + head * HD);
    const float4* qp1 = (const float4*)(Q + (size_t)(qbase + row1) * C + head * HD);
    float4 q0[10], q1[10];
#pragma unroll
    for (int i = 0; i < 10; ++i) { q0[i] = qp0[i]; q1[i] = qp1[i]; }

    __syncthreads();

    float l0 = 0.f, l1 = 0.f;
    float4 o0[10], o1[10];
#pragma unroll
    for (int i = 0; i < 10; ++i) {
        o0[i] = make_float4(0.f, 0.f, 0.f, 0.f);
        o1[i] = make_float4(0.f, 0.f, 0.f, 0.f);
    }

    for (int j = 0; j < L; ++j) {
        const float4* kj = &ksv[j * 10];
        float4 a0 = make_float4(0.f, 0.f, 0.f, 0.f);
        float4 a1 = make_float4(0.f, 0.f, 0.f, 0.f);
#pragma unroll
        for (int i = 0; i < 10; ++i) {
            float4 kk = kj[i];
            a0.x = fmaf(q0[i].x, kk.x, a0.x);
            a0.y = fmaf(q0[i].y, kk.y, a0.y);
            a0.z = fmaf(q0[i].z, kk.z, a0.z);
            a0.w = fmaf(q0[i].w, kk.w, a0.w);
            a1.x = fmaf(q1[i].x, kk.x, a1.x);
            a1.y = fmaf(q1[i].y, kk.y, a1.y);
            a1.z = fmaf(q1[i].z, kk.z, a1.z);
            a1.w = fmaf(q1[i].w, kk.w, a1.w);
        }
        float p0 = __expf(((a0.x + a0.y) + (a0.z + a0.w)) * SCALE);
        float p1 = __expf(((a1.x + a1.y) + (a1.z + a1.w)) * SCALE);
        l0 += p0;
        l1 += p1;
        const float4* vj = &vsv[j * 10];
#pragma unroll
        for (int i = 0; i < 10; ++i) {
            float4 vv = vj[i];
            o0[i].x = fmaf(p0, vv.x, o0[i].x);
            o0[i].y = fmaf(p0, vv.y, o0[i].y);
            o0[i].z = fmaf(p0, vv.z, o0[i].z);
            o0[i].w = fmaf(p0, vv.w, o0[i].w);
            o1[i].x = fmaf(p1, vv.x, o1[i].x);
            o1[i].y = fmaf(p1, vv.y, o1[i].y);
            o1[i].z = fmaf(p1, vv.z, o1[i].z);
            o1[i].w = fmaf(p1, vv.w, o1[i].w);
        }
    }

    float r0, r1;
    _Float16 *xp0, *xp1;
    if (b == 0) {
        r0 = 1.0f / l0; r1 = 1.0f / l1;
        xp0 = Xh + (size_t)row0 * C + head * HD;
        xp1 = Xh + (size_t)row1 * C + head * HD;
    } else {
        r0 = wPh[(size_t)(b - 1) * HW + row0] / l0;
        r1 = wPh[(size_t)(b - 1) * HW + row1] / l1;
        xp0 = Xall + ((size_t)(b - 1) * HW + row0) * C + head * HD;
        xp1 = Xall + ((size_t)(b - 1) * HW + row1) * C + head * HD;
    }
#pragma unroll
    for (int i = 0; i < 10; ++i) {
        float4 v0 = o0[i], v1 = o1[i];
        half4v h0 = {(_Float16)(v0.x * r0), (_Float16)(v0.y * r0),
                     (_Float16)(v0.z * r0), (_Float16)(v0.w * r0)};
        half4v h1 = {(_Float16)(v1.x * r1), (_Float16)(v1.y * r1),
                     (_Float16)(v1.z * r1), (_Float16)(v1.w * r1)};
        *(half4v*)(xp0 + i * 4) = h0;
        *(half4v*)(xp1 + i * 4) = h1;
    }
}

// ---------------------------------------------------------------------------
// Reduce the 9 per-batch f16 contributions into Xh rows 4096..8191 (f16).
// ---------------------------------------------------------------------------
__global__ __launch_bounds__(256) void reduce_f16(const _Float16* __restrict__ Xall,
                                                  _Float16* __restrict__ Xh) {
    size_t idx = ((size_t)blockIdx.x * 256 + threadIdx.x) * 8;
    const size_t slot = (size_t)HW * C;
    float s[8] = {0.f,0.f,0.f,0.f,0.f,0.f,0.f,0.f};
#pragma unroll
    for (int b = 0; b < 9; ++b) {
        half8v v = *(const half8v*)(Xall + (size_t)b * slot + idx);
#pragma unroll
        for (int i = 0; i < 8; ++i) s[i] += (float)v[i];
    }
    half8v o;
#pragma unroll
    for (int i = 0; i < 8; ++i) o[i] = (_Float16)s[i];
    *(half8v*)(Xh + slot + idx) = o;
}

// ---------------------------------------------------------------------------
// Launch
// ---------------------------------------------------------------------------
extern "C" void kernel_launch(void* const* d_in, const int* in_sizes, int n_in,
                              void* d_out, int out_size, void* d_ws, size_t ws_size,
                              hipStream_t stream) {
    const float* hs   = (const float*)d_in[0];
    const float* ehs  = (const float*)d_in[1];
    const float* bbox = (const float*)d_in[2];
    const float* Wq   = (const float*)d_in[3];
    const float* Wk   = (const float*)d_in[4];
    const float* Wv   = (const float*)d_in[5];
    const float* Wo   = (const float*)d_in[6];
    const float* bo   = (const float*)d_in[7];
    float* out = (float*)d_out;

    // fp32 region
    float* Qbuf  = (float*)d_ws;                         // 8192*320
    float* KVbuf = Qbuf + (size_t)2 * HW * C;            // 770*640
    float* wPh   = KVbuf + (size_t)NB * L * KVC;         // 9*4096
    float* wSum  = wPh + (size_t)9 * HW;                 // 4096
    // f16 region (16B-aligned by construction)
    _Float16* hsH  = (_Float16*)(wSum + HW);             // 8192*320
    _Float16* ehsH = hsH + (size_t)2 * HW * C;           // 770*768
    _Float16* WqT  = ehsH + (size_t)NB * L * CX;         // 320*320
    _Float16* WkvT = WqT + (size_t)C * C;                // 640*768
    _Float16* WoT  = WkvT + (size_t)KVC * CX;            // 320*320
    _Float16* Xh   = WoT + (size_t)C * C;                // 8192*320
    _Float16* Xall = Xh + (size_t)2 * HW * C;            // 9*4096*320

    maskw_kernel<<<dim3(HW / 256), 256, 0, stream>>>(bbox, wPh, wSum);
    cvt_f16<<<dim3((2 * HW * C / 4) / 256), 256, 0, stream>>>(hs, hsH, 2 * HW * C / 4);
    cvt_f16<<<dim3((NB * L * CX / 4 + 255) / 256), 256, 0, stream>>>(ehs, ehsH, NB * L * CX / 4);
    wpackT<<<dim3(C / 64, C / 64), 256, 0, stream>>>(Wq, WqT, C, C);
    wpackT<<<dim3(C / 64, CX / 64), 256, 0, stream>>>(Wk, WkvT, CX, C);
    wpackT<<<dim3(C / 64, CX / 64), 256, 0, stream>>>(Wv, WkvT + (size_t)C * CX, CX, C);
    wpackT<<<dim3(C / 64, C / 64), 256, 0, stream>>>(Wo, WoT, C, C);
    gemm_f16<<<dim3(C / 64, (2 * HW) / 64), 256, 0, stream>>>(hsH, WqT, Qbuf, 2 * HW, C, C);
    gemm_f16<<<dim3(KVC / 64, (NB * L + 63) / 64), 256, 0, stream>>>(ehsH, WkvT, KVbuf, NB * L, KVC, CX);
    attn_kernel<<<dim3(NB * NH * 16), 128, 0, stream>>>(Qbuf, KVbuf, wPh, Xh, Xall);
    reduce_f16<<<dim3((HW * C / 8) / 256), 256, 0, stream>>>(Xall, Xh);
    gemm_oproj_f16<<<dim3(C / 64, (2 * HW) / 64), 256, 0, stream>>>(Xh, WoT, bo, wSum, out);
}

// Round 5
// 196.558 us; speedup vs baseline: 4.3892x; 1.1773x over previous
//
#include <hip/hip_runtime.h>
#include <math.h>

// Problem constants
#define HW 4096
#define C 320
#define CX 768
#define L 77
#define NB 10
#define NH 8
#define HD 40
#define NINST 8
#define KVC 640
#define SCALE 0.15811388300841898f  // 1/sqrt(40)
#define PSTR 104                    // P LDS stride in halves (2-way banks, 16B aligned)

typedef _Float16 half8v __attribute__((ext_vector_type(8)));
typedef _Float16 half4v __attribute__((ext_vector_type(4)));
typedef float f32x4 __attribute__((ext_vector_type(4)));

// ---------------------------------------------------------------------------
// Mask / phase weights. Separable antialiased resize profiles computed once
// per block in LDS (per-thread tap work 256 -> ~34), grid 16 blocks x 256.
// ---------------------------------------------------------------------------
__device__ __forceinline__ float axis_profile(int o, float lo, float hi) {
    float num = 0.f, den = 0.f;
    int j0 = 8 * o - 4;
#pragma unroll
    for (int t = 0; t < 16; ++t) {
        int j = j0 + t;
        float wt = 1.0f - fabsf((float)t - 7.5f) * 0.125f;
        if (j >= 0 && j < 512) {
            den += wt;
            float fj = (float)j;
            if (fj >= lo && fj < hi) num += wt;
        }
    }
    return num / den;
}

__global__ __launch_bounds__(256) void maskw_kernel(const float* __restrict__ bboxes,
                                                    float* __restrict__ wPh,
                                                    float* __restrict__ wSum) {
    __shared__ float sw_s[NINST][64];
    __shared__ float sh_s[NINST][4];
    int tid = threadIdx.x;
    int oyb = blockIdx.x * 4;
    for (int i = tid; i < NINST * 64; i += 256) {
        int n = i >> 6, ox = i & 63;
        float lo = floorf(512.f * bboxes[n * 4 + 0]);
        float hi = floorf(512.f * bboxes[n * 4 + 2]);
        sw_s[n][ox] = axis_profile(ox, lo, hi);
    }
    if (tid < NINST * 4) {
        int n = tid >> 2, oy = tid & 3;
        float lo = floorf(512.f * bboxes[n * 4 + 1]);
        float hi = floorf(512.f * bboxes[n * 4 + 3]);
        sh_s[n][oy] = axis_profile(oyb + oy, lo, hi);
    }
    __syncthreads();
    int oy = tid >> 6, ox = tid & 63;
    int hw = (oyb + oy) * 64 + ox;
    float sum = 0.1f;
    wPh[hw] = 0.1f;
#pragma unroll
    for (int n = 0; n < NINST; ++n) {
        float wv = 10.f * sh_s[n][oy] * sw_s[n][ox];
        wPh[(n + 1) * HW + hw] = wv;
        sum += wv;
    }
    wSum[hw] = sum;
}

// ---------------------------------------------------------------------------
// fp32 -> f16 convert
// ---------------------------------------------------------------------------
__global__ __launch_bounds__(256) void cvt_f16(const float* __restrict__ src,
                                               _Float16* __restrict__ dst, int n4) {
    int i = blockIdx.x * 256 + threadIdx.x;
    if (i >= n4) return;
    float4 v = ((const float4*)src)[i];
    half4v h = {(_Float16)v.x, (_Float16)v.y, (_Float16)v.z, (_Float16)v.w};
    ((half4v*)dst)[i] = h;
}

// ---------------------------------------------------------------------------
// Weight transpose+pack: W (K x N fp32) -> WT (N x K f16)
// ---------------------------------------------------------------------------
__global__ __launch_bounds__(256) void wpackT(const float* __restrict__ W,
                                              _Float16* __restrict__ WT,
                                              int K, int N) {
    __shared__ float tile[64][65];
    int nt = blockIdx.x * 64, kt = blockIdx.y * 64;
#pragma unroll
    for (int p = 0; p < 16; ++p) {
        int idx = p * 256 + threadIdx.x;
        int k = idx >> 6, n = idx & 63;
        tile[k][n] = W[(size_t)(kt + k) * N + nt + n];
    }
    __syncthreads();
#pragma unroll
    for (int p = 0; p < 16; ++p) {
        int idx = p * 256 + threadIdx.x;
        int n = idx >> 6, k = idx & 63;
        WT[(size_t)(nt + n) * K + kt + k] = (_Float16)tile[k][n];
    }
}

// ---------------------------------------------------------------------------
// Q projection: Qh(8192, 512) f16 = hsH(8192,320) @ WqT^T, cols remapped to
// per-head-64 padded layout (h*64 + d); pad cols pre-zeroed by memset.
// ---------------------------------------------------------------------------
__global__ __launch_bounds__(256) void gemm_qproj(const _Float16* __restrict__ A,
                                                  const _Float16* __restrict__ BT,
                                                  _Float16* __restrict__ Qh) {
    const int K = C;
    int lane = threadIdx.x & 63, wave = threadIdx.x >> 6;
    int m0 = blockIdx.y * 64 + wave * 16;
    int n0 = blockIdx.x * 64;
    int lr = lane & 15, kq = (lane >> 4) * 8;
    const _Float16* ap = A + (size_t)(m0 + lr) * K + kq;
    const _Float16* bp = BT + (size_t)(n0 + lr) * K + kq;
    f32x4 acc0 = {0.f,0.f,0.f,0.f}, acc1 = acc0, acc2 = acc0, acc3 = acc0;
    for (int k0 = 0; k0 < K; k0 += 32) {
        half8v af = *(const half8v*)(ap + k0);
        half8v b0 = *(const half8v*)(bp + k0);
        half8v b1 = *(const half8v*)(bp + (size_t)16 * K + k0);
        half8v b2 = *(const half8v*)(bp + (size_t)32 * K + k0);
        half8v b3 = *(const half8v*)(bp + (size_t)48 * K + k0);
        acc0 = __builtin_amdgcn_mfma_f32_16x16x32_f16(af, b0, acc0, 0, 0, 0);
        acc1 = __builtin_amdgcn_mfma_f32_16x16x32_f16(af, b1, acc1, 0, 0, 0);
        acc2 = __builtin_amdgcn_mfma_f32_16x16x32_f16(af, b2, acc2, 0, 0, 0);
        acc3 = __builtin_amdgcn_mfma_f32_16x16x32_f16(af, b3, acc3, 0, 0, 0);
    }
    int rb = m0 + ((lane >> 4) << 2);
    f32x4 accs[4] = {acc0, acc1, acc2, acc3};
#pragma unroll
    for (int t = 0; t < 4; ++t) {
        int col = n0 + t * 16 + lr;
        int h = col / 40;
        int d = col - h * 40;
#pragma unroll
        for (int r = 0; r < 4; ++r)
            Qh[(size_t)(rb + r) * 512 + h * 64 + d] = (_Float16)accs[t][r];
    }
}

// ---------------------------------------------------------------------------
// K/V projection: KVh(800,640) f16, rows remapped b*80 + j (j<77); pad rows
// untouched (attention masks them).
// ---------------------------------------------------------------------------
__global__ __launch_bounds__(256) void gemm_kv(const _Float16* __restrict__ A,
                                               const _Float16* __restrict__ BT,
                                               _Float16* __restrict__ KVh) {
    const int K = CX, M = NB * L;
    int lane = threadIdx.x & 63, wave = threadIdx.x >> 6;
    int m0 = blockIdx.y * 64 + wave * 16;
    int n0 = blockIdx.x * 64;
    int lr = lane & 15, kq = (lane >> 4) * 8;
    int arow = m0 + lr; if (arow >= M) arow = M - 1;
    const _Float16* ap = A + (size_t)arow * K + kq;
    const _Float16* bp = BT + (size_t)(n0 + lr) * K + kq;
    f32x4 acc0 = {0.f,0.f,0.f,0.f}, acc1 = acc0, acc2 = acc0, acc3 = acc0;
    for (int k0 = 0; k0 < K; k0 += 32) {
        half8v af = *(const half8v*)(ap + k0);
        half8v b0 = *(const half8v*)(bp + k0);
        half8v b1 = *(const half8v*)(bp + (size_t)16 * K + k0);
        half8v b2 = *(const half8v*)(bp + (size_t)32 * K + k0);
        half8v b3 = *(const half8v*)(bp + (size_t)48 * K + k0);
        acc0 = __builtin_amdgcn_mfma_f32_16x16x32_f16(af, b0, acc0, 0, 0, 0);
        acc1 = __builtin_amdgcn_mfma_f32_16x16x32_f16(af, b1, acc1, 0, 0, 0);
        acc2 = __builtin_amdgcn_mfma_f32_16x16x32_f16(af, b2, acc2, 0, 0, 0);
        acc3 = __builtin_amdgcn_mfma_f32_16x16x32_f16(af, b3, acc3, 0, 0, 0);
    }
    int rb = m0 + ((lane >> 4) << 2);
    f32x4 accs[4] = {acc0, acc1, acc2, acc3};
#pragma unroll
    for (int t = 0; t < 4; ++t) {
        int col = n0 + t * 16 + lr;
#pragma unroll
        for (int r = 0; r < 4; ++r) {
            int row = rb + r;
            if (row < M) {
                int bb = row / 77;
                int orow = bb * 80 + (row - bb * 77);
                KVh[(size_t)orow * KVC + col] = (_Float16)accs[t][r];
            }
        }
    }
}

// ---------------------------------------------------------------------------
// V transpose: KVh V-region -> VTg (b,h,48,96) f16, zero-padded (d 40..47,
// key 77..95) so padded P / padded d contribute exactly 0 in PV MFMA.
// ---------------------------------------------------------------------------
__global__ __launch_bounds__(256) void vtrans(const _Float16* __restrict__ KVh,
                                              _Float16* __restrict__ VTg) {
    int b = blockIdx.x >> 3, h = blockIdx.x & 7;
    _Float16* dst = VTg + (size_t)blockIdx.x * 48 * 96;
    for (int idx = threadIdx.x; idx < 48 * 96; idx += 256) {
        int key = idx / 48, d = idx - key * 48;
        _Float16 v = (_Float16)0.f;
        if (d < 40 && key < 77)
            v = KVh[(size_t)(b * 80 + key) * KVC + C + h * HD + d];
        dst[(size_t)d * 96 + key] = v;
    }
}

// ---------------------------------------------------------------------------
// MFMA attention. Block = 4 waves; wave handles 16 query rows for one head,
// looping all 10 batches (b=0 uncond -> write rows 0..4095; b=1..9 cond ->
// f32 accumulate, write fused rows 4096..8191 once). Fragments load directly
// from global (L2-resident); P transposes through per-wave LDS. Q pad zeros
// nullify K-fragment column spill; VTg zeros nullify P padding.
// ---------------------------------------------------------------------------
__global__ __launch_bounds__(256) void attn_mfma(const _Float16* __restrict__ Qh,   // (8192,512)
                                                 const _Float16* __restrict__ KVh,  // (800,640)
                                                 const _Float16* __restrict__ VTg,  // (80,48,96)
                                                 const float* __restrict__ wPh,     // (9,HW)
                                                 _Float16* __restrict__ Xh) {       // (8192,320)
    __shared__ _Float16 plds[4][16 * PSTR];
    int wave = threadIdx.x >> 6, lane = threadIdx.x & 63;
    int head = blockIdx.x >> 6;
    int qg = blockIdx.x & 63;
    int qrow0 = qg * 64 + wave * 16;
    int c = lane & 15, quad = lane >> 4;
    _Float16* pl = &plds[wave][0];

    // zero P LDS keys 80..95 (never written per-iter; must be 0, not garbage)
#pragma unroll
    for (int i = 0; i < 4; ++i) {
        int idx = i * 64 + lane;           // 0..255
        int m = idx >> 4, kk = idx & 15;
        pl[m * PSTR + 80 + kk] = (_Float16)0.f;
    }

    // Q A-fragments (once; cond Q shared across b=1..9)
    const _Float16* qu = Qh + (size_t)(qrow0 + c) * 512 + head * 64 + quad * 8;
    const _Float16* qc = qu + (size_t)HW * 512;
    half8v qa_u0 = *(const half8v*)(qu);
    half8v qa_u1 = *(const half8v*)(qu + 32);
    half8v qa_c0 = *(const half8v*)(qc);
    half8v qa_c1 = *(const half8v*)(qc + 32);

    f32x4 oacc0 = {0.f,0.f,0.f,0.f}, oacc1 = oacc0, oacc2 = oacc0;

    for (int b = 0; b < NB; ++b) {
        half8v a0 = b ? qa_c0 : qa_u0;
        half8v a1 = b ? qa_c1 : qa_u1;

        // ---- QK^T: 5 key tiles x (K=64 via 2 mfma) ----
        f32x4 sc[5];
        const _Float16* kb = KVh + (size_t)(b * 80 + c) * KVC + head * HD + quad * 8;
#pragma unroll
        for (int t = 0; t < 5; ++t) {
            const _Float16* kt = kb + (size_t)t * 16 * KVC;
            half8v b0 = *(const half8v*)(kt);
            half8v b1 = *(const half8v*)(kt + 32);
            f32x4 acc = {0.f,0.f,0.f,0.f};
            acc = __builtin_amdgcn_mfma_f32_16x16x32_f16(a0, b0, acc, 0, 0, 0);
            acc = __builtin_amdgcn_mfma_f32_16x16x32_f16(a1, b1, acc, 0, 0, 0);
            sc[t] = acc;
        }

        // ---- softmax (no max-sub: logits are small) ----
        float pv[5][4];
        float lsum[4] = {0.f, 0.f, 0.f, 0.f};
        bool lastpad = (c >= 13);
#pragma unroll
        for (int t = 0; t < 5; ++t) {
#pragma unroll
            for (int r = 0; r < 4; ++r) {
                float p = __expf(sc[t][r] * SCALE);
                if (t == 4 && lastpad) p = 0.f;   // keys 77..79 (also kills NaN)
                pv[t][r] = p;
                lsum[r] += p;
            }
        }
#pragma unroll
        for (int m = 1; m < 16; m <<= 1) {
#pragma unroll
            for (int r = 0; r < 4; ++r) lsum[r] += __shfl_xor(lsum[r], m, 64);
        }

        // ---- P -> LDS (C-layout -> A-layout transpose) ----
#pragma unroll
        for (int t = 0; t < 5; ++t) {
#pragma unroll
            for (int r = 0; r < 4; ++r)
                pl[(quad * 4 + r) * PSTR + t * 16 + c] = (_Float16)pv[t][r];
        }
        // intra-wave LDS RAW: in-order DS pipe + compiler waitcnt; no barrier.

        // ---- PV: out 3 d-tiles x (K=96 via 3 mfma) ----
        half8v pa0 = *(const half8v*)(pl + (size_t)c * PSTR + 0  + quad * 8);
        half8v pa1 = *(const half8v*)(pl + (size_t)c * PSTR + 32 + quad * 8);
        half8v pa2 = *(const half8v*)(pl + (size_t)c * PSTR + 64 + quad * 8);
        const _Float16* vb = VTg + ((size_t)(b * 8 + head) * 48 + c) * 96 + quad * 8;
        f32x4 pvo[3];
#pragma unroll
        for (int t = 0; t < 3; ++t) {
            const _Float16* vt = vb + (size_t)t * 16 * 96;
            half8v v0 = *(const half8v*)(vt);
            half8v v1 = *(const half8v*)(vt + 32);
            half8v v2 = *(const half8v*)(vt + 64);
            f32x4 acc = {0.f,0.f,0.f,0.f};
            acc = __builtin_amdgcn_mfma_f32_16x16x32_f16(pa0, v0, acc, 0, 0, 0);
            acc = __builtin_amdgcn_mfma_f32_16x16x32_f16(pa1, v1, acc, 0, 0, 0);
            acc = __builtin_amdgcn_mfma_f32_16x16x32_f16(pa2, v2, acc, 0, 0, 0);
            pvo[t] = acc;
        }

        // ---- epilogue ----
        if (b == 0) {
            float rin[4];
#pragma unroll
            for (int r = 0; r < 4; ++r) rin[r] = 1.0f / lsum[r];
#pragma unroll
            for (int t = 0; t < 3; ++t) {
                int col = t * 16 + c;
                if (col < HD) {
#pragma unroll
                    for (int r = 0; r < 4; ++r) {
                        int row = qrow0 + quad * 4 + r;
                        Xh[(size_t)row * C + head * HD + col] = (_Float16)(pvo[t][r] * rin[r]);
                    }
                }
            }
        } else {
            float rf[4];
#pragma unroll
            for (int r = 0; r < 4; ++r) {
                int row = qrow0 + quad * 4 + r;
                rf[r] = wPh[(size_t)(b - 1) * HW + row] / lsum[r];
            }
#pragma unroll
            for (int r = 0; r < 4; ++r) {
                oacc0[r] += pvo[0][r] * rf[r];
                oacc1[r] += pvo[1][r] * rf[r];
                oacc2[r] += pvo[2][r] * rf[r];
            }
        }
    }

    // write fused cond rows
    f32x4 oa[3] = {oacc0, oacc1, oacc2};
#pragma unroll
    for (int t = 0; t < 3; ++t) {
        int col = t * 16 + c;
        if (col < HD) {
#pragma unroll
            for (int r = 0; r < 4; ++r) {
                int row = HW + qrow0 + quad * 4 + r;
                Xh[(size_t)row * C + head * HD + col] = (_Float16)oa[t][r];
            }
        }
    }
}

// ---------------------------------------------------------------------------
// O-projection f16 MFMA GEMM with fused epilogue (unchanged from round 4)
// ---------------------------------------------------------------------------
__global__ __launch_bounds__(256) void gemm_oproj_f16(const _Float16* __restrict__ A,
                                                      const _Float16* __restrict__ BT,
                                                      const float* __restrict__ bo,
                                                      const float* __restrict__ wSum,
                                                      float* __restrict__ Out) {
    const int K = C;
    int lane = threadIdx.x & 63, wave = threadIdx.x >> 6;
    int m0 = blockIdx.y * 64 + wave * 16;
    int n0 = blockIdx.x * 64;
    int lr = lane & 15, kq = (lane >> 4) * 8;
    const _Float16* ap = A + (size_t)(m0 + lr) * K + kq;
    const _Float16* bp = BT + (size_t)(n0 + lr) * K + kq;
    f32x4 acc0 = {0.f,0.f,0.f,0.f}, acc1 = acc0, acc2 = acc0, acc3 = acc0;
    for (int k0 = 0; k0 < K; k0 += 32) {
        half8v af = *(const half8v*)(ap + k0);
        half8v b0 = *(const half8v*)(bp + k0);
        half8v b1 = *(const half8v*)(bp + (size_t)16 * K + k0);
        half8v b2 = *(const half8v*)(bp + (size_t)32 * K + k0);
        half8v b3 = *(const half8v*)(bp + (size_t)48 * K + k0);
        acc0 = __builtin_amdgcn_mfma_f32_16x16x32_f16(af, b0, acc0, 0, 0, 0);
        acc1 = __builtin_amdgcn_mfma_f32_16x16x32_f16(af, b1, acc1, 0, 0, 0);
        acc2 = __builtin_amdgcn_mfma_f32_16x16x32_f16(af, b2, acc2, 0, 0, 0);
        acc3 = __builtin_amdgcn_mfma_f32_16x16x32_f16(af, b3, acc3, 0, 0, 0);
    }
    int rb = m0 + ((lane >> 4) << 2);
    f32x4 accs[4] = {acc0, acc1, acc2, acc3};
#pragma unroll
    for (int t = 0; t < 4; ++t) {
        int col = n0 + t * 16 + lr;
        float bv = bo[col];
#pragma unroll
        for (int r = 0; r < 4; ++r) {
            int row = rb + r;
            float v = accs[t][r];
            if (row < HW) {
                v += bv;
            } else {
                float ws = wSum[row - HW];
                v = (v + bv * ws) / (ws + 1e-6f);
            }
            Out[(size_t)row * C + col] = v;
        }
    }
}

// ---------------------------------------------------------------------------
// Launch
// ---------------------------------------------------------------------------
extern "C" void kernel_launch(void* const* d_in, const int* in_sizes, int n_in,
                              void* d_out, int out_size, void* d_ws, size_t ws_size,
                              hipStream_t stream) {
    const float* hs   = (const float*)d_in[0];
    const float* ehs  = (const float*)d_in[1];
    const float* bbox = (const float*)d_in[2];
    const float* Wq   = (const float*)d_in[3];
    const float* Wk   = (const float*)d_in[4];
    const float* Wv   = (const float*)d_in[5];
    const float* Wo   = (const float*)d_in[6];
    const float* bo   = (const float*)d_in[7];
    float* out = (float*)d_out;

    float* wPh  = (float*)d_ws;                          // 9*4096
    float* wSum = wPh + (size_t)9 * HW;                  // 4096
    _Float16* hsH  = (_Float16*)(wSum + HW);             // 8192*320
    _Float16* ehsH = hsH + (size_t)2 * HW * C;           // 770*768
    _Float16* WqT  = ehsH + (size_t)NB * L * CX;         // 320*320
    _Float16* WkvT = WqT + (size_t)C * C;                // 640*768
    _Float16* WoT  = WkvT + (size_t)KVC * CX;            // 320*320
    _Float16* Qh   = WoT + (size_t)C * C;                // 8192*512 (per-head 64 pad)
    _Float16* KVh  = Qh + (size_t)2 * HW * 512;          // 800*640 (rows b*80+j)
    _Float16* VTg  = KVh + (size_t)800 * KVC;            // 80*48*96
    _Float16* Xh   = VTg + (size_t)80 * 48 * 96;         // 8192*320

    maskw_kernel<<<dim3(16), 256, 0, stream>>>(bbox, wPh, wSum);
    cvt_f16<<<dim3((2 * HW * C / 4) / 256), 256, 0, stream>>>(hs, hsH, 2 * HW * C / 4);
    cvt_f16<<<dim3((NB * L * CX / 4 + 255) / 256), 256, 0, stream>>>(ehs, ehsH, NB * L * CX / 4);
    wpackT<<<dim3(C / 64, C / 64), 256, 0, stream>>>(Wq, WqT, C, C);
    wpackT<<<dim3(C / 64, CX / 64), 256, 0, stream>>>(Wk, WkvT, CX, C);
    wpackT<<<dim3(C / 64, CX / 64), 256, 0, stream>>>(Wv, WkvT + (size_t)C * CX, CX, C);
    wpackT<<<dim3(C / 64, C / 64), 256, 0, stream>>>(Wo, WoT, C, C);
    hipMemsetAsync((void*)Qh, 0, (size_t)2 * HW * 512 * sizeof(_Float16), stream);
    gemm_qproj<<<dim3(C / 64, (2 * HW) / 64), 256, 0, stream>>>(hsH, WqT, Qh);
    gemm_kv<<<dim3(KVC / 64, (NB * L + 63) / 64), 256, 0, stream>>>(ehsH, WkvT, KVh);
    vtrans<<<dim3(NB * NH), 256, 0, stream>>>(KVh, VTg);
    attn_mfma<<<dim3(NH * 64), 256, 0, stream>>>(Qh, KVh, VTg, wPh, Xh);
    gemm_oproj_f16<<<dim3(C / 64, (2 * HW) / 64), 256, 0, stream>>>(Xh, WoT, bo, wSum, out);
}

// Round 6
// 185.703 us; speedup vs baseline: 4.6458x; 1.0585x over previous
//
#include <hip/hip_runtime.h>
#include <math.h>

// Problem constants
#define HW 4096
#define C 320
#define CX 768
#define L 77
#define NB 10
#define NH 8
#define HD 40
#define NINST 8
#define KVC 640
#define SCALE 0.15811388300841898f  // 1/sqrt(40)
#define PSTR 104                    // P LDS stride in halves

typedef _Float16 half8v __attribute__((ext_vector_type(8)));
typedef _Float16 half4v __attribute__((ext_vector_type(4)));
typedef float f32x4 __attribute__((ext_vector_type(4)));

// ---------------------------------------------------------------------------
// Mask / phase weights (separable antialiased resize, profiles in LDS).
// ---------------------------------------------------------------------------
__device__ __forceinline__ float axis_profile(int o, float lo, float hi) {
    float num = 0.f, den = 0.f;
    int j0 = 8 * o - 4;
#pragma unroll
    for (int t = 0; t < 16; ++t) {
        int j = j0 + t;
        float wt = 1.0f - fabsf((float)t - 7.5f) * 0.125f;
        if (j >= 0 && j < 512) {
            den += wt;
            float fj = (float)j;
            if (fj >= lo && fj < hi) num += wt;
        }
    }
    return num / den;
}

__global__ __launch_bounds__(256) void maskw_kernel(const float* __restrict__ bboxes,
                                                    float* __restrict__ wPh,
                                                    float* __restrict__ wSum) {
    __shared__ float sw_s[NINST][64];
    __shared__ float sh_s[NINST][4];
    int tid = threadIdx.x;
    int oyb = blockIdx.x * 4;
    for (int i = tid; i < NINST * 64; i += 256) {
        int n = i >> 6, ox = i & 63;
        float lo = floorf(512.f * bboxes[n * 4 + 0]);
        float hi = floorf(512.f * bboxes[n * 4 + 2]);
        sw_s[n][ox] = axis_profile(ox, lo, hi);
    }
    if (tid < NINST * 4) {
        int n = tid >> 2, oy = tid & 3;
        float lo = floorf(512.f * bboxes[n * 4 + 1]);
        float hi = floorf(512.f * bboxes[n * 4 + 3]);
        sh_s[n][oy] = axis_profile(oyb + oy, lo, hi);
    }
    __syncthreads();
    int oy = tid >> 6, ox = tid & 63;
    int hw = (oyb + oy) * 64 + ox;
    float sum = 0.1f;
    wPh[hw] = 0.1f;
#pragma unroll
    for (int n = 0; n < NINST; ++n) {
        float wv = 10.f * sh_s[n][oy] * sw_s[n][ox];
        wPh[(n + 1) * HW + hw] = wv;
        sum += wv;
    }
    wSum[hw] = sum;
}

// ---------------------------------------------------------------------------
// Fused fp32->f16 convert for hs and ehs in one dispatch.
// ---------------------------------------------------------------------------
__global__ __launch_bounds__(256) void cvt_all(const float* __restrict__ hs,
                                               const float* __restrict__ ehs,
                                               _Float16* __restrict__ hsH,
                                               _Float16* __restrict__ ehsH) {
    const int n1 = 2 * HW * C / 4;
    const int n2 = NB * L * CX / 4;
    int i = blockIdx.x * 256 + threadIdx.x;
    const float* src; _Float16* dst;
    if (i < n1) { src = hs; dst = hsH; }
    else if (i < n1 + n2) { i -= n1; src = ehs; dst = ehsH; }
    else return;
    float4 v = ((const float4*)src)[i];
    half4v h = {(_Float16)v.x, (_Float16)v.y, (_Float16)v.z, (_Float16)v.w};
    ((half4v*)dst)[i] = h;
}

// ---------------------------------------------------------------------------
// All four weight transposes in one dispatch (z selects the weight).
// W (K x 320 fp32) -> WT (320 x K f16).
// ---------------------------------------------------------------------------
__global__ __launch_bounds__(256) void wpack_all(const float* __restrict__ Wq,
                                                 const float* __restrict__ Wk,
                                                 const float* __restrict__ Wv,
                                                 const float* __restrict__ Wo,
                                                 _Float16* __restrict__ WqT,
                                                 _Float16* __restrict__ WkvT,
                                                 _Float16* __restrict__ WoT) {
    const float* W; _Float16* WT; int K;
    int z = blockIdx.z;
    if (z == 0)      { W = Wq; WT = WqT; K = C; }
    else if (z == 1) { W = Wk; WT = WkvT; K = CX; }
    else if (z == 2) { W = Wv; WT = WkvT + (size_t)C * CX; K = CX; }
    else             { W = Wo; WT = WoT; K = C; }
    int kt = blockIdx.y * 64;
    if (kt >= K) return;
    int nt = blockIdx.x * 64;
    __shared__ float tile[64][65];
#pragma unroll
    for (int p = 0; p < 16; ++p) {
        int idx = p * 256 + threadIdx.x;
        int k = idx >> 6, n = idx & 63;
        tile[k][n] = W[(size_t)(kt + k) * C + nt + n];
    }
    __syncthreads();
#pragma unroll
    for (int p = 0; p < 16; ++p) {
        int idx = p * 256 + threadIdx.x;
        int n = idx >> 6, k = idx & 63;
        WT[(size_t)(nt + n) * K + kt + k] = (_Float16)tile[k][n];
    }
}

// ---------------------------------------------------------------------------
// Q projection: Qh(8192,320) f16 = hsH @ WqT^T. Plain row-major output
// (padding eliminated; attn zeros the spill fragment in-register).
// ---------------------------------------------------------------------------
__global__ __launch_bounds__(256) void gemm_qproj(const _Float16* __restrict__ A,
                                                  const _Float16* __restrict__ BT,
                                                  _Float16* __restrict__ Qh) {
    const int K = C;
    int lane = threadIdx.x & 63, wave = threadIdx.x >> 6;
    int m0 = blockIdx.y * 64 + wave * 16;
    int n0 = blockIdx.x * 64;
    int lr = lane & 15, kq = (lane >> 4) * 8;
    const _Float16* ap = A + (size_t)(m0 + lr) * K + kq;
    const _Float16* bp = BT + (size_t)(n0 + lr) * K + kq;
    f32x4 acc0 = {0.f,0.f,0.f,0.f}, acc1 = acc0, acc2 = acc0, acc3 = acc0;
    for (int k0 = 0; k0 < K; k0 += 32) {
        half8v af = *(const half8v*)(ap + k0);
        half8v b0 = *(const half8v*)(bp + k0);
        half8v b1 = *(const half8v*)(bp + (size_t)16 * K + k0);
        half8v b2 = *(const half8v*)(bp + (size_t)32 * K + k0);
        half8v b3 = *(const half8v*)(bp + (size_t)48 * K + k0);
        acc0 = __builtin_amdgcn_mfma_f32_16x16x32_f16(af, b0, acc0, 0, 0, 0);
        acc1 = __builtin_amdgcn_mfma_f32_16x16x32_f16(af, b1, acc1, 0, 0, 0);
        acc2 = __builtin_amdgcn_mfma_f32_16x16x32_f16(af, b2, acc2, 0, 0, 0);
        acc3 = __builtin_amdgcn_mfma_f32_16x16x32_f16(af, b3, acc3, 0, 0, 0);
    }
    int rb = m0 + ((lane >> 4) << 2);
    f32x4 accs[4] = {acc0, acc1, acc2, acc3};
#pragma unroll
    for (int t = 0; t < 4; ++t) {
        int col = n0 + t * 16 + lr;
#pragma unroll
        for (int r = 0; r < 4; ++r)
            Qh[(size_t)(rb + r) * C + col] = (_Float16)accs[t][r];
    }
}

// ---------------------------------------------------------------------------
// K/V projection: KVh(800,640) f16, rows remapped b*80+j (j<77).
// ---------------------------------------------------------------------------
__global__ __launch_bounds__(256) void gemm_kv(const _Float16* __restrict__ A,
                                               const _Float16* __restrict__ BT,
                                               _Float16* __restrict__ KVh) {
    const int K = CX, M = NB * L;
    int lane = threadIdx.x & 63, wave = threadIdx.x >> 6;
    int m0 = blockIdx.y * 64 + wave * 16;
    int n0 = blockIdx.x * 64;
    int lr = lane & 15, kq = (lane >> 4) * 8;
    int arow = m0 + lr; if (arow >= M) arow = M - 1;
    const _Float16* ap = A + (size_t)arow * K + kq;
    const _Float16* bp = BT + (size_t)(n0 + lr) * K + kq;
    f32x4 acc0 = {0.f,0.f,0.f,0.f}, acc1 = acc0, acc2 = acc0, acc3 = acc0;
    for (int k0 = 0; k0 < K; k0 += 32) {
        half8v af = *(const half8v*)(ap + k0);
        half8v b0 = *(const half8v*)(bp + k0);
        half8v b1 = *(const half8v*)(bp + (size_t)16 * K + k0);
        half8v b2 = *(const half8v*)(bp + (size_t)32 * K + k0);
        half8v b3 = *(const half8v*)(bp + (size_t)48 * K + k0);
        acc0 = __builtin_amdgcn_mfma_f32_16x16x32_f16(af, b0, acc0, 0, 0, 0);
        acc1 = __builtin_amdgcn_mfma_f32_16x16x32_f16(af, b1, acc1, 0, 0, 0);
        acc2 = __builtin_amdgcn_mfma_f32_16x16x32_f16(af, b2, acc2, 0, 0, 0);
        acc3 = __builtin_amdgcn_mfma_f32_16x16x32_f16(af, b3, acc3, 0, 0, 0);
    }
    int rb = m0 + ((lane >> 4) << 2);
    f32x4 accs[4] = {acc0, acc1, acc2, acc3};
#pragma unroll
    for (int t = 0; t < 4; ++t) {
        int col = n0 + t * 16 + lr;
#pragma unroll
        for (int r = 0; r < 4; ++r) {
            int row = rb + r;
            if (row < M) {
                int bb = row / 77;
                int orow = bb * 80 + (row - bb * 77);
                KVh[(size_t)orow * KVC + col] = (_Float16)accs[t][r];
            }
        }
    }
}

// ---------------------------------------------------------------------------
// V transpose: -> VTg (b,h,48,96) f16, zero-padded.
// ---------------------------------------------------------------------------
__global__ __launch_bounds__(256) void vtrans(const _Float16* __restrict__ KVh,
                                              _Float16* __restrict__ VTg) {
    int b = blockIdx.x >> 3, h = blockIdx.x & 7;
    _Float16* dst = VTg + (size_t)blockIdx.x * 48 * 96;
    for (int idx = threadIdx.x; idx < 48 * 96; idx += 256) {
        int key = idx / 48, d = idx - key * 48;
        _Float16 v = (_Float16)0.f;
        if (d < 40 && key < 77)
            v = KVh[(size_t)(b * 80 + key) * KVC + C + h * HD + d];
        dst[(size_t)d * 96 + key] = v;
    }
}

// ---------------------------------------------------------------------------
// MFMA attention, batch-pair interleaved (2 independent QK/softmax/PV chains
// per iteration -> 2x ILP at 2 waves/SIMD). Wave = 16 q-rows of one head.
// Pairs: (uncond b0, b1), (b2,b3), (b4,b5), (b6,b7), (b8,b9).
// Q second K-chunk fragment zeroed in-register for quads 1..3 (no Q padding);
// MFMA A-side zeros nullify B-side spill garbage.
// ---------------------------------------------------------------------------
__global__ __launch_bounds__(256, 2) void attn_mfma(const _Float16* __restrict__ Qh,   // (8192,320)
                                                    const _Float16* __restrict__ KVh,  // (800,640)
                                                    const _Float16* __restrict__ VTg,  // (80,48,96)
                                                    const float* __restrict__ wPh,     // (9,HW)
                                                    _Float16* __restrict__ Xh) {       // (8192,320)
    __shared__ _Float16 plds[4][2][16 * PSTR];
    int wave = threadIdx.x >> 6, lane = threadIdx.x & 63;
    int head = blockIdx.x >> 6;
    int qg = blockIdx.x & 63;
    int qrow0 = qg * 64 + wave * 16;
    int c = lane & 15, quad = lane >> 4;
    _Float16* pl0 = &plds[wave][0][0];
    _Float16* pl1 = &plds[wave][1][0];

    // zero P pad keys 80..95 in both buffers (512 halves, 8 per lane)
#pragma unroll
    for (int i = 0; i < 8; ++i) {
        int idx = i * 64 + lane;
        int buf = idx >> 8;
        int rem = idx & 255;
        int m = rem >> 4, kk = rem & 15;
        plds[wave][buf][m * PSTR + 80 + kk] = (_Float16)0.f;
    }

    // Q fragments (row m = qrow0 + c); frag1 valid only for quad 0 (d 32..39)
    const _Float16* qu = Qh + (size_t)(qrow0 + c) * C + head * HD + quad * 8;
    const _Float16* qc = qu + (size_t)HW * C;
    half8v zero8 = {(_Float16)0.f,(_Float16)0.f,(_Float16)0.f,(_Float16)0.f,
                    (_Float16)0.f,(_Float16)0.f,(_Float16)0.f,(_Float16)0.f};
    half8v qa_u0 = *(const half8v*)(qu);
    half8v qa_c0 = *(const half8v*)(qc);
    half8v qa_u1 = zero8, qa_c1 = zero8;
    if (quad == 0) {
        qa_u1 = *(const half8v*)(qu + 32);
        qa_c1 = *(const half8v*)(qc + 32);
    }

    f32x4 oacc0 = {0.f,0.f,0.f,0.f}, oacc1 = oacc0, oacc2 = oacc0;
    bool lastpad = (c >= 13);

    for (int p = 0; p < 5; ++p) {
        int bx = 2 * p, by = 2 * p + 1;
        bool xu = (p == 0);
        half8v ax0 = xu ? qa_u0 : qa_c0;
        half8v ax1 = xu ? qa_u1 : qa_c1;

        // ---- QK^T for both items ----
        f32x4 scx[5], scy[5];
        const _Float16* kbx = KVh + (size_t)(bx * 80 + c) * KVC + head * HD + quad * 8;
        const _Float16* kby = KVh + (size_t)(by * 80 + c) * KVC + head * HD + quad * 8;
#pragma unroll
        for (int t = 0; t < 5; ++t) {
            const _Float16* ktx = kbx + (size_t)t * 16 * KVC;
            const _Float16* kty = kby + (size_t)t * 16 * KVC;
            half8v bx0 = *(const half8v*)(ktx);
            half8v bx1 = *(const half8v*)(ktx + 32);
            half8v by0 = *(const half8v*)(kty);
            half8v by1 = *(const half8v*)(kty + 32);
            f32x4 ax = {0.f,0.f,0.f,0.f};
            ax = __builtin_amdgcn_mfma_f32_16x16x32_f16(ax0, bx0, ax, 0, 0, 0);
            ax = __builtin_amdgcn_mfma_f32_16x16x32_f16(ax1, bx1, ax, 0, 0, 0);
            scx[t] = ax;
            f32x4 ay = {0.f,0.f,0.f,0.f};
            ay = __builtin_amdgcn_mfma_f32_16x16x32_f16(qa_c0, by0, ay, 0, 0, 0);
            ay = __builtin_amdgcn_mfma_f32_16x16x32_f16(qa_c1, by1, ay, 0, 0, 0);
            scy[t] = ay;
        }

        // ---- softmax both ----
        float px[5][4], py[5][4];
        float lx[4] = {0.f,0.f,0.f,0.f}, ly[4] = {0.f,0.f,0.f,0.f};
#pragma unroll
        for (int t = 0; t < 5; ++t) {
#pragma unroll
            for (int r = 0; r < 4; ++r) {
                float ex = __expf(scx[t][r] * SCALE);
                float ey = __expf(scy[t][r] * SCALE);
                if (t == 4 && lastpad) { ex = 0.f; ey = 0.f; }
                px[t][r] = ex; py[t][r] = ey;
                lx[r] += ex; ly[r] += ey;
            }
        }
#pragma unroll
        for (int m = 1; m < 16; m <<= 1) {
#pragma unroll
            for (int r = 0; r < 4; ++r) {
                lx[r] += __shfl_xor(lx[r], m, 64);
                ly[r] += __shfl_xor(ly[r], m, 64);
            }
        }

        // ---- P -> LDS (C-layout -> A-layout) ----
#pragma unroll
        for (int t = 0; t < 5; ++t) {
#pragma unroll
            for (int r = 0; r < 4; ++r) {
                pl0[(quad * 4 + r) * PSTR + t * 16 + c] = (_Float16)px[t][r];
                pl1[(quad * 4 + r) * PSTR + t * 16 + c] = (_Float16)py[t][r];
            }
        }
        // intra-wave LDS RAW: in-order DS pipe + compiler waitcnt (verified r5)

        // ---- PV both ----
        half8v pax0 = *(const half8v*)(pl0 + (size_t)c * PSTR + 0  + quad * 8);
        half8v pax1 = *(const half8v*)(pl0 + (size_t)c * PSTR + 32 + quad * 8);
        half8v pax2 = *(const half8v*)(pl0 + (size_t)c * PSTR + 64 + quad * 8);
        half8v pay0 = *(const half8v*)(pl1 + (size_t)c * PSTR + 0  + quad * 8);
        half8v pay1 = *(const half8v*)(pl1 + (size_t)c * PSTR + 32 + quad * 8);
        half8v pay2 = *(const half8v*)(pl1 + (size_t)c * PSTR + 64 + quad * 8);
        const _Float16* vbx = VTg + ((size_t)(bx * 8 + head) * 48 + c) * 96 + quad * 8;
        const _Float16* vby = VTg + ((size_t)(by * 8 + head) * 48 + c) * 96 + quad * 8;
        f32x4 pvx[3], pvy[3];
#pragma unroll
        for (int t = 0; t < 3; ++t) {
            const _Float16* vtx = vbx + (size_t)t * 16 * 96;
            const _Float16* vty = vby + (size_t)t * 16 * 96;
            half8v vx0 = *(const half8v*)(vtx);
            half8v vx1 = *(const half8v*)(vtx + 32);
            half8v vx2 = *(const half8v*)(vtx + 64);
            half8v vy0 = *(const half8v*)(vty);
            half8v vy1 = *(const half8v*)(vty + 32);
            half8v vy2 = *(const half8v*)(vty + 64);
            f32x4 ax = {0.f,0.f,0.f,0.f};
            ax = __builtin_amdgcn_mfma_f32_16x16x32_f16(pax0, vx0, ax, 0, 0, 0);
            ax = __builtin_amdgcn_mfma_f32_16x16x32_f16(pax1, vx1, ax, 0, 0, 0);
            ax = __builtin_amdgcn_mfma_f32_16x16x32_f16(pax2, vx2, ax, 0, 0, 0);
            pvx[t] = ax;
            f32x4 ay = {0.f,0.f,0.f,0.f};
            ay = __builtin_amdgcn_mfma_f32_16x16x32_f16(pay0, vy0, ay, 0, 0, 0);
            ay = __builtin_amdgcn_mfma_f32_16x16x32_f16(pay1, vy1, ay, 0, 0, 0);
            ay = __builtin_amdgcn_mfma_f32_16x16x32_f16(pay2, vy2, ay, 0, 0, 0);
            pvy[t] = ay;
        }

        // ---- epilogue ----
        if (xu) {
            float rin[4];
#pragma unroll
            for (int r = 0; r < 4; ++r) rin[r] = 1.0f / lx[r];
#pragma unroll
            for (int t = 0; t < 3; ++t) {
                int col = t * 16 + c;
                if (col < HD) {
#pragma unroll
                    for (int r = 0; r < 4; ++r) {
                        int row = qrow0 + quad * 4 + r;
                        Xh[(size_t)row * C + head * HD + col] = (_Float16)(pvx[t][r] * rin[r]);
                    }
                }
            }
        } else {
            float rfx[4];
#pragma unroll
            for (int r = 0; r < 4; ++r) {
                int row = qrow0 + quad * 4 + r;
                rfx[r] = wPh[(size_t)(bx - 1) * HW + row] / lx[r];
            }
#pragma unroll
            for (int r = 0; r < 4; ++r) {
                oacc0[r] += pvx[0][r] * rfx[r];
                oacc1[r] += pvx[1][r] * rfx[r];
                oacc2[r] += pvx[2][r] * rfx[r];
            }
        }
        {
            float rfy[4];
#pragma unroll
            for (int r = 0; r < 4; ++r) {
                int row = qrow0 + quad * 4 + r;
                rfy[r] = wPh[(size_t)(by - 1) * HW + row] / ly[r];
            }
#pragma unroll
            for (int r = 0; r < 4; ++r) {
                oacc0[r] += pvy[0][r] * rfy[r];
                oacc1[r] += pvy[1][r] * rfy[r];
                oacc2[r] += pvy[2][r] * rfy[r];
            }
        }
    }

    // write fused cond rows
    f32x4 oa[3] = {oacc0, oacc1, oacc2};
#pragma unroll
    for (int t = 0; t < 3; ++t) {
        int col = t * 16 + c;
        if (col < HD) {
#pragma unroll
            for (int r = 0; r < 4; ++r) {
                int row = HW + qrow0 + quad * 4 + r;
                Xh[(size_t)row * C + head * HD + col] = (_Float16)oa[t][r];
            }
        }
    }
}

// ---------------------------------------------------------------------------
// O-projection f16 MFMA GEMM with fused epilogue.
// ---------------------------------------------------------------------------
__global__ __launch_bounds__(256) void gemm_oproj_f16(const _Float16* __restrict__ A,
                                                      const _Float16* __restrict__ BT,
                                                      const float* __restrict__ bo,
                                                      const float* __restrict__ wSum,
                                                      float* __restrict__ Out) {
    const int K = C;
    int lane = threadIdx.x & 63, wave = threadIdx.x >> 6;
    int m0 = blockIdx.y * 64 + wave * 16;
    int n0 = blockIdx.x * 64;
    int lr = lane & 15, kq = (lane >> 4) * 8;
    const _Float16* ap = A + (size_t)(m0 + lr) * K + kq;
    const _Float16* bp = BT + (size_t)(n0 + lr) * K + kq;
    f32x4 acc0 = {0.f,0.f,0.f,0.f}, acc1 = acc0, acc2 = acc0, acc3 = acc0;
    for (int k0 = 0; k0 < K; k0 += 32) {
        half8v af = *(const half8v*)(ap + k0);
        half8v b0 = *(const half8v*)(bp + k0);
        half8v b1 = *(const half8v*)(bp + (size_t)16 * K + k0);
        half8v b2 = *(const half8v*)(bp + (size_t)32 * K + k0);
        half8v b3 = *(const half8v*)(bp + (size_t)48 * K + k0);
        acc0 = __builtin_amdgcn_mfma_f32_16x16x32_f16(af, b0, acc0, 0, 0, 0);
        acc1 = __builtin_amdgcn_mfma_f32_16x16x32_f16(af, b1, acc1, 0, 0, 0);
        acc2 = __builtin_amdgcn_mfma_f32_16x16x32_f16(af, b2, acc2, 0, 0, 0);
        acc3 = __builtin_amdgcn_mfma_f32_16x16x32_f16(af, b3, acc3, 0, 0, 0);
    }
    int rb = m0 + ((lane >> 4) << 2);
    f32x4 accs[4] = {acc0, acc1, acc2, acc3};
#pragma unroll
    for (int t = 0; t < 4; ++t) {
        int col = n0 + t * 16 + lr;
        float bv = bo[col];
#pragma unroll
        for (int r = 0; r < 4; ++r) {
            int row = rb + r;
            float v = accs[t][r];
            if (row < HW) {
                v += bv;
            } else {
                float ws = wSum[row - HW];
                v = (v + bv * ws) / (ws + 1e-6f);
            }
            Out[(size_t)row * C + col] = v;
        }
    }
}

// ---------------------------------------------------------------------------
// Launch
// ---------------------------------------------------------------------------
extern "C" void kernel_launch(void* const* d_in, const int* in_sizes, int n_in,
                              void* d_out, int out_size, void* d_ws, size_t ws_size,
                              hipStream_t stream) {
    const float* hs   = (const float*)d_in[0];
    const float* ehs  = (const float*)d_in[1];
    const float* bbox = (const float*)d_in[2];
    const float* Wq   = (const float*)d_in[3];
    const float* Wk   = (const float*)d_in[4];
    const float* Wv   = (const float*)d_in[5];
    const float* Wo   = (const float*)d_in[6];
    const float* bo   = (const float*)d_in[7];
    float* out = (float*)d_out;

    float* wPh  = (float*)d_ws;                          // 9*4096
    float* wSum = wPh + (size_t)9 * HW;                  // 4096
    _Float16* hsH  = (_Float16*)(wSum + HW);             // 8192*320
    _Float16* ehsH = hsH + (size_t)2 * HW * C;           // 770*768
    _Float16* WqT  = ehsH + (size_t)NB * L * CX;         // 320*320
    _Float16* WkvT = WqT + (size_t)C * C;                // 640*768
    _Float16* WoT  = WkvT + (size_t)KVC * CX;            // 320*320
    _Float16* Qh   = WoT + (size_t)C * C;                // 8192*320
    _Float16* KVh  = Qh + (size_t)2 * HW * C;            // 800*640
    _Float16* VTg  = KVh + (size_t)800 * KVC;            // 80*48*96
    _Float16* Xh   = VTg + (size_t)80 * 48 * 96;         // 8192*320

    const int nCvt = (2 * HW * C + NB * L * CX) / 4;
    maskw_kernel<<<dim3(16), 256, 0, stream>>>(bbox, wPh, wSum);
    cvt_all<<<dim3((nCvt + 255) / 256), 256, 0, stream>>>(hs, ehs, hsH, ehsH);
    wpack_all<<<dim3(C / 64, CX / 64, 4), 256, 0, stream>>>(Wq, Wk, Wv, Wo, WqT, WkvT, WoT);
    gemm_qproj<<<dim3(C / 64, (2 * HW) / 64), 256, 0, stream>>>(hsH, WqT, Qh);
    gemm_kv<<<dim3(KVC / 64, (NB * L + 63) / 64), 256, 0, stream>>>(ehsH, WkvT, KVh);
    vtrans<<<dim3(NB * NH), 256, 0, stream>>>(KVh, VTg);
    attn_mfma<<<dim3(NH * 64), 256, 0, stream>>>(Qh, KVh, VTg, wPh, Xh);
    gemm_oproj_f16<<<dim3(C / 64, (2 * HW) / 64), 256, 0, stream>>>(Xh, WoT, bo, wSum, out);
}

// Round 7
// 167.747 us; speedup vs baseline: 5.1431x; 1.1070x over previous
//
#include <hip/hip_runtime.h>
#include <math.h>

// Problem constants
#define HW 4096
#define C 320
#define CX 768
#define L 77
#define NB 10
#define NH 8
#define HD 40
#define NINST 8
#define KVC 640
#define SCALE 0.15811388300841898f  // 1/sqrt(40)
#define PSTR 104                    // LDS row stride in halves

typedef _Float16 half8v __attribute__((ext_vector_type(8)));
typedef _Float16 half4v __attribute__((ext_vector_type(4)));
typedef float f32x4 __attribute__((ext_vector_type(4)));

// prep grid segmentation
#define SEG_MASK   16
#define N_CVT1     (2 * HW * C / 4)          // 655360 float4s (hs)
#define N_CVT2     (NB * L * CX / 4)         // 147840 float4s (ehs)
#define SEG_CVT    (((N_CVT1 + N_CVT2) + 255) / 256)   // 3138
#define SEG_WPACK  240                        // 4 weights x 12 x 5 (early-exit)
#define SEG_VTZ    180                        // 80*48*96/8/256
#define NPREP      (SEG_MASK + SEG_CVT + SEG_WPACK + SEG_VTZ)

// ---------------------------------------------------------------------------
// prep: maskw + cvt(hs,ehs) + weight packs + VTg zero, one dispatch.
// ---------------------------------------------------------------------------
__device__ __forceinline__ float axis_profile(int o, float lo, float hi) {
    float num = 0.f, den = 0.f;
    int j0 = 8 * o - 4;
#pragma unroll
    for (int t = 0; t < 16; ++t) {
        int j = j0 + t;
        float wt = 1.0f - fabsf((float)t - 7.5f) * 0.125f;
        if (j >= 0 && j < 512) {
            den += wt;
            float fj = (float)j;
            if (fj >= lo && fj < hi) num += wt;
        }
    }
    return num / den;
}

__global__ __launch_bounds__(256) void prep_kernel(
        const float* __restrict__ bboxes,
        const float* __restrict__ hs, const float* __restrict__ ehs,
        const float* __restrict__ Wq, const float* __restrict__ Wk,
        const float* __restrict__ Wv, const float* __restrict__ Wo,
        float* __restrict__ wPh, float* __restrict__ wSum,
        _Float16* __restrict__ hsH, _Float16* __restrict__ ehsH,
        _Float16* __restrict__ WqT, _Float16* __restrict__ WkvT,
        _Float16* __restrict__ WoT, _Float16* __restrict__ VTg) {
    __shared__ float tile[64][65];
    __shared__ float sw_s[NINST][64];
    __shared__ float sh_s[NINST][4];
    int bx = blockIdx.x, tid = threadIdx.x;

    if (bx < SEG_MASK) {
        // ---- mask / phase weights ----
        int oyb = bx * 4;
        for (int i = tid; i < NINST * 64; i += 256) {
            int n = i >> 6, ox = i & 63;
            float lo = floorf(512.f * bboxes[n * 4 + 0]);
            float hi = floorf(512.f * bboxes[n * 4 + 2]);
            sw_s[n][ox] = axis_profile(ox, lo, hi);
        }
        if (tid < NINST * 4) {
            int n = tid >> 2, oy = tid & 3;
            float lo = floorf(512.f * bboxes[n * 4 + 1]);
            float hi = floorf(512.f * bboxes[n * 4 + 3]);
            sh_s[n][oy] = axis_profile(oyb + oy, lo, hi);
        }
        __syncthreads();
        int oy = tid >> 6, ox = tid & 63;
        int hw = (oyb + oy) * 64 + ox;
        float sum = 0.1f;
        wPh[hw] = 0.1f;
#pragma unroll
        for (int n = 0; n < NINST; ++n) {
            float wv = 10.f * sh_s[n][oy] * sw_s[n][ox];
            wPh[(n + 1) * HW + hw] = wv;
            sum += wv;
        }
        wSum[hw] = sum;
    } else if (bx < SEG_MASK + SEG_CVT) {
        // ---- fp32 -> f16 convert ----
        int i = (bx - SEG_MASK) * 256 + tid;
        const float* src; _Float16* dst;
        if (i < N_CVT1) { src = hs; dst = hsH; }
        else if (i < N_CVT1 + N_CVT2) { i -= N_CVT1; src = ehs; dst = ehsH; }
        else return;
        float4 v = ((const float4*)src)[i];
        half4v h = {(_Float16)v.x, (_Float16)v.y, (_Float16)v.z, (_Float16)v.w};
        ((half4v*)dst)[i] = h;
    } else if (bx < SEG_MASK + SEG_CVT + SEG_WPACK) {
        // ---- weight transpose+pack: W (K x 320 fp32) -> WT (320 x K f16) ----
        int zz = bx - SEG_MASK - SEG_CVT;       // 0..239
        int z = zz / 60, inner = zz - z * 60;
        int by = inner / 5, bx2 = inner - by * 5;
        const float* W; _Float16* WT; int K;
        if (z == 0)      { W = Wq; WT = WqT; K = C; }
        else if (z == 1) { W = Wk; WT = WkvT; K = CX; }
        else if (z == 2) { W = Wv; WT = WkvT + (size_t)C * CX; K = CX; }
        else             { W = Wo; WT = WoT; K = C; }
        int kt = by * 64;
        if (kt >= K) return;
        int nt = bx2 * 64;
#pragma unroll
        for (int p = 0; p < 16; ++p) {
            int idx = p * 256 + tid;
            int k = idx >> 6, n = idx & 63;
            tile[k][n] = W[(size_t)(kt + k) * C + nt + n];
        }
        __syncthreads();
#pragma unroll
        for (int p = 0; p < 16; ++p) {
            int idx = p * 256 + tid;
            int n = idx >> 6, k = idx & 63;
            WT[(size_t)(nt + n) * K + kt + k] = (_Float16)tile[k][n];
        }
    } else {
        // ---- VTg zero (pad keys/dims must be exact zeros) ----
        int i = (bx - SEG_MASK - SEG_CVT - SEG_WPACK) * 256 + tid;  // 0..46079
        half8v z8 = {(_Float16)0.f,(_Float16)0.f,(_Float16)0.f,(_Float16)0.f,
                     (_Float16)0.f,(_Float16)0.f,(_Float16)0.f,(_Float16)0.f};
        ((half8v*)VTg)[i] = z8;
    }
}

// ---------------------------------------------------------------------------
// K/V projection. K half (cols<320) -> Kh(800,320), rows b*80+j.
// V half (cols>=320) -> stored DIRECTLY TRANSPOSED into VTg (b,h,48,96)
// (scatter f16 stores, 0.5 MB total; kills the vtrans dispatch).
// ---------------------------------------------------------------------------
__global__ __launch_bounds__(256) void gemm_kv(const _Float16* __restrict__ A,
                                               const _Float16* __restrict__ BT,
                                               _Float16* __restrict__ Kh,
                                               _Float16* __restrict__ VTg) {
    const int K = CX, M = NB * L;
    int lane = threadIdx.x & 63, wave = threadIdx.x >> 6;
    int m0 = blockIdx.y * 64 + wave * 16;
    int n0 = blockIdx.x * 64;
    int lr = lane & 15, kq = (lane >> 4) * 8;
    int arow = m0 + lr; if (arow >= M) arow = M - 1;
    const _Float16* ap = A + (size_t)arow * K + kq;
    const _Float16* bp = BT + (size_t)(n0 + lr) * K + kq;
    f32x4 acc0 = {0.f,0.f,0.f,0.f}, acc1 = acc0, acc2 = acc0, acc3 = acc0;
    for (int k0 = 0; k0 < K; k0 += 32) {
        half8v af = *(const half8v*)(ap + k0);
        half8v b0 = *(const half8v*)(bp + k0);
        half8v b1 = *(const half8v*)(bp + (size_t)16 * K + k0);
        half8v b2 = *(const half8v*)(bp + (size_t)32 * K + k0);
        half8v b3 = *(const half8v*)(bp + (size_t)48 * K + k0);
        acc0 = __builtin_amdgcn_mfma_f32_16x16x32_f16(af, b0, acc0, 0, 0, 0);
        acc1 = __builtin_amdgcn_mfma_f32_16x16x32_f16(af, b1, acc1, 0, 0, 0);
        acc2 = __builtin_amdgcn_mfma_f32_16x16x32_f16(af, b2, acc2, 0, 0, 0);
        acc3 = __builtin_amdgcn_mfma_f32_16x16x32_f16(af, b3, acc3, 0, 0, 0);
    }
    int rb = m0 + ((lane >> 4) << 2);
    f32x4 accs[4] = {acc0, acc1, acc2, acc3};
#pragma unroll
    for (int t = 0; t < 4; ++t) {
        int col = n0 + t * 16 + lr;
#pragma unroll
        for (int r = 0; r < 4; ++r) {
            int row = rb + r;
            if (row < M) {
                int bb = row / 77;
                int key = row - bb * 77;
                if (col < C) {
                    Kh[(size_t)(bb * 80 + key) * C + col] = (_Float16)accs[t][r];
                } else {
                    int ch = col - C;
                    int h = ch / HD;
                    int d = ch - h * HD;
                    VTg[((size_t)(bb * 8 + h) * 48 + d) * 96 + key] = (_Float16)accs[t][r];
                }
            }
        }
    }
}

// ---------------------------------------------------------------------------
// MFMA attention with FUSED Q-projection. Block = (head, 64-q-row group),
// wave = 16 q-rows. Phase 1: compute Q tile (uncond+cond) via MFMA from hsH
// and WqT, transpose through LDS into A-layout (pad cols 40..63 pre-zeroed).
// Phase 2: batch-pair interleaved QK/softmax/PV (pairs (0,1),(2,3)..(8,9)),
// cond batches f32-accumulated, written once.
// ---------------------------------------------------------------------------
__global__ __launch_bounds__(256, 2) void attn_mfma(const _Float16* __restrict__ hsH,  // (8192,320)
                                                    const _Float16* __restrict__ WqT,  // (320,320)
                                                    const _Float16* __restrict__ Kh,   // (800,320)
                                                    const _Float16* __restrict__ VTg,  // (80,48,96)
                                                    const float* __restrict__ wPh,     // (9,HW)
                                                    _Float16* __restrict__ Xh) {       // (8192,320)
    __shared__ _Float16 plds[4][2][16 * PSTR];
    int wave = threadIdx.x >> 6, lane = threadIdx.x & 63;
    int head = blockIdx.x >> 6;
    int qg = blockIdx.x & 63;
    int qrow0 = qg * 64 + wave * 16;
    int c = lane & 15, quad = lane >> 4;
    _Float16* pl0 = &plds[wave][0][0];
    _Float16* pl1 = &plds[wave][1][0];
    half8v zero8 = {(_Float16)0.f,(_Float16)0.f,(_Float16)0.f,(_Float16)0.f,
                    (_Float16)0.f,(_Float16)0.f,(_Float16)0.f,(_Float16)0.f};

    // pre-zero LDS cols 40..95 of all 16 rows, both buffers (7 half8s/row)
#pragma unroll
    for (int i = 0; i < 4; ++i) {
        int idx = i * 64 + lane;            // 0..255, need 224
        if (idx < 224) {
            int buf = idx / 112;
            int rem = idx - buf * 112;
            int row = rem / 7, c8 = rem - row * 7;
            *(half8v*)&plds[wave][buf][row * PSTR + 40 + c8 * 8] = zero8;
        }
    }

    // ---- Phase 1: Q projection (uncond -> pl0, cond -> pl1) ----
    {
        const _Float16* au_p = hsH + (size_t)(qrow0 + c) * C + quad * 8;
        const _Float16* ac_p = au_p + (size_t)HW * C;
        f32x4 qa[2][3] = {};
        for (int k0 = 0; k0 < C; k0 += 32) {
            half8v au = *(const half8v*)(au_p + k0);
            half8v ac = *(const half8v*)(ac_p + k0);
#pragma unroll
            for (int t = 0; t < 3; ++t) {
                const _Float16* bp = WqT + (size_t)(head * HD + t * 16 + c) * C + quad * 8 + k0;
                half8v bf = *(const half8v*)bp;
                qa[0][t] = __builtin_amdgcn_mfma_f32_16x16x32_f16(au, bf, qa[0][t], 0, 0, 0);
                qa[1][t] = __builtin_amdgcn_mfma_f32_16x16x32_f16(ac, bf, qa[1][t], 0, 0, 0);
            }
        }
        // C-layout -> LDS rows (transpose); only cols < 40 are real
#pragma unroll
        for (int t = 0; t < 3; ++t) {
            if (t < 2 || c < 8) {
#pragma unroll
                for (int r = 0; r < 4; ++r) {
                    pl0[(quad * 4 + r) * PSTR + t * 16 + c] = (_Float16)qa[0][t][r];
                    pl1[(quad * 4 + r) * PSTR + t * 16 + c] = (_Float16)qa[1][t][r];
                }
            }
        }
    }
    // intra-wave LDS RAW: in-order DS pipe + compiler waitcnt (r5/r6 verified)
    half8v qa_u0 = *(const half8v*)(pl0 + (size_t)c * PSTR + quad * 8);
    half8v qa_u1 = *(const half8v*)(pl0 + (size_t)c * PSTR + 32 + quad * 8);
    half8v qa_c0 = *(const half8v*)(pl1 + (size_t)c * PSTR + quad * 8);
    half8v qa_c1 = *(const half8v*)(pl1 + (size_t)c * PSTR + 32 + quad * 8);

    f32x4 oacc0 = {0.f,0.f,0.f,0.f}, oacc1 = oacc0, oacc2 = oacc0;
    bool lastpad = (c >= 13);

    // ---- Phase 2: batch pairs ----
    for (int p = 0; p < 5; ++p) {
        int bx = 2 * p, by = 2 * p + 1;
        bool xu = (p == 0);
        half8v ax0 = xu ? qa_u0 : qa_c0;
        half8v ax1 = xu ? qa_u1 : qa_c1;

        // QK^T both
        f32x4 scx[5], scy[5];
        const _Float16* kbx = Kh + (size_t)(bx * 80 + c) * C + head * HD + quad * 8;
        const _Float16* kby = Kh + (size_t)(by * 80 + c) * C + head * HD + quad * 8;
#pragma unroll
        for (int t = 0; t < 5; ++t) {
            const _Float16* ktx = kbx + (size_t)t * 16 * C;
            const _Float16* kty = kby + (size_t)t * 16 * C;
            half8v bx0 = *(const half8v*)(ktx);
            half8v bx1 = *(const half8v*)(ktx + 32);
            half8v by0 = *(const half8v*)(kty);
            half8v by1 = *(const half8v*)(kty + 32);
            f32x4 ax = {0.f,0.f,0.f,0.f};
            ax = __builtin_amdgcn_mfma_f32_16x16x32_f16(ax0, bx0, ax, 0, 0, 0);
            ax = __builtin_amdgcn_mfma_f32_16x16x32_f16(ax1, bx1, ax, 0, 0, 0);
            scx[t] = ax;
            f32x4 ay = {0.f,0.f,0.f,0.f};
            ay = __builtin_amdgcn_mfma_f32_16x16x32_f16(qa_c0, by0, ay, 0, 0, 0);
            ay = __builtin_amdgcn_mfma_f32_16x16x32_f16(qa_c1, by1, ay, 0, 0, 0);
            scy[t] = ay;
        }

        // softmax both (no max-sub: logits small)
        float px[5][4], py[5][4];
        float lx[4] = {0.f,0.f,0.f,0.f}, ly[4] = {0.f,0.f,0.f,0.f};
#pragma unroll
        for (int t = 0; t < 5; ++t) {
#pragma unroll
            for (int r = 0; r < 4; ++r) {
                float ex = __expf(scx[t][r] * SCALE);
                float ey = __expf(scy[t][r] * SCALE);
                if (t == 4 && lastpad) { ex = 0.f; ey = 0.f; }
                px[t][r] = ex; py[t][r] = ey;
                lx[r] += ex; ly[r] += ey;
            }
        }
#pragma unroll
        for (int m = 1; m < 16; m <<= 1) {
#pragma unroll
            for (int r = 0; r < 4; ++r) {
                lx[r] += __shfl_xor(lx[r], m, 64);
                ly[r] += __shfl_xor(ly[r], m, 64);
            }
        }

        // P -> LDS (C-layout -> A-layout)
#pragma unroll
        for (int t = 0; t < 5; ++t) {
#pragma unroll
            for (int r = 0; r < 4; ++r) {
                pl0[(quad * 4 + r) * PSTR + t * 16 + c] = (_Float16)px[t][r];
                pl1[(quad * 4 + r) * PSTR + t * 16 + c] = (_Float16)py[t][r];
            }
        }

        // PV both
        half8v pax0 = *(const half8v*)(pl0 + (size_t)c * PSTR + 0  + quad * 8);
        half8v pax1 = *(const half8v*)(pl0 + (size_t)c * PSTR + 32 + quad * 8);
        half8v pax2 = *(const half8v*)(pl0 + (size_t)c * PSTR + 64 + quad * 8);
        half8v pay0 = *(const half8v*)(pl1 + (size_t)c * PSTR + 0  + quad * 8);
        half8v pay1 = *(const half8v*)(pl1 + (size_t)c * PSTR + 32 + quad * 8);
        half8v pay2 = *(const half8v*)(pl1 + (size_t)c * PSTR + 64 + quad * 8);
        const _Float16* vbx = VTg + ((size_t)(bx * 8 + head) * 48 + c) * 96 + quad * 8;
        const _Float16* vby = VTg + ((size_t)(by * 8 + head) * 48 + c) * 96 + quad * 8;
        f32x4 pvx[3], pvy[3];
#pragma unroll
        for (int t = 0; t < 3; ++t) {
            const _Float16* vtx = vbx + (size_t)t * 16 * 96;
            const _Float16* vty = vby + (size_t)t * 16 * 96;
            half8v vx0 = *(const half8v*)(vtx);
            half8v vx1 = *(const half8v*)(vtx + 32);
            half8v vx2 = *(const half8v*)(vtx + 64);
            half8v vy0 = *(const half8v*)(vty);
            half8v vy1 = *(const half8v*)(vty + 32);
            half8v vy2 = *(const half8v*)(vty + 64);
            f32x4 ax = {0.f,0.f,0.f,0.f};
            ax = __builtin_amdgcn_mfma_f32_16x16x32_f16(pax0, vx0, ax, 0, 0, 0);
            ax = __builtin_amdgcn_mfma_f32_16x16x32_f16(pax1, vx1, ax, 0, 0, 0);
            ax = __builtin_amdgcn_mfma_f32_16x16x32_f16(pax2, vx2, ax, 0, 0, 0);
            pvx[t] = ax;
            f32x4 ay = {0.f,0.f,0.f,0.f};
            ay = __builtin_amdgcn_mfma_f32_16x16x32_f16(pay0, vy0, ay, 0, 0, 0);
            ay = __builtin_amdgcn_mfma_f32_16x16x32_f16(pay1, vy1, ay, 0, 0, 0);
            ay = __builtin_amdgcn_mfma_f32_16x16x32_f16(pay2, vy2, ay, 0, 0, 0);
            pvy[t] = ay;
        }

        // epilogue
        if (xu) {
            float rin[4];
#pragma unroll
            for (int r = 0; r < 4; ++r) rin[r] = 1.0f / lx[r];
#pragma unroll
            for (int t = 0; t < 3; ++t) {
                int col = t * 16 + c;
                if (col < HD) {
#pragma unroll
                    for (int r = 0; r < 4; ++r) {
                        int row = qrow0 + quad * 4 + r;
                        Xh[(size_t)row * C + head * HD + col] = (_Float16)(pvx[t][r] * rin[r]);
                    }
                }
            }
        } else {
            float rfx[4];
#pragma unroll
            for (int r = 0; r < 4; ++r) {
                int row = qrow0 + quad * 4 + r;
                rfx[r] = wPh[(size_t)(bx - 1) * HW + row] / lx[r];
            }
#pragma unroll
            for (int r = 0; r < 4; ++r) {
                oacc0[r] += pvx[0][r] * rfx[r];
                oacc1[r] += pvx[1][r] * rfx[r];
                oacc2[r] += pvx[2][r] * rfx[r];
            }
        }
        {
            float rfy[4];
#pragma unroll
            for (int r = 0; r < 4; ++r) {
                int row = qrow0 + quad * 4 + r;
                rfy[r] = wPh[(size_t)(by - 1) * HW + row] / ly[r];
            }
#pragma unroll
            for (int r = 0; r < 4; ++r) {
                oacc0[r] += pvy[0][r] * rfy[r];
                oacc1[r] += pvy[1][r] * rfy[r];
                oacc2[r] += pvy[2][r] * rfy[r];
            }
        }
    }

    // write fused cond rows
    f32x4 oa[3] = {oacc0, oacc1, oacc2};
#pragma unroll
    for (int t = 0; t < 3; ++t) {
        int col = t * 16 + c;
        if (col < HD) {
#pragma unroll
            for (int r = 0; r < 4; ++r) {
                int row = HW + qrow0 + quad * 4 + r;
                Xh[(size_t)row * C + head * HD + col] = (_Float16)oa[t][r];
            }
        }
    }
}

// ---------------------------------------------------------------------------
// O-projection f16 MFMA GEMM with fused epilogue.
// ---------------------------------------------------------------------------
__global__ __launch_bounds__(256) void gemm_oproj_f16(const _Float16* __restrict__ A,
                                                      const _Float16* __restrict__ BT,
                                                      const float* __restrict__ bo,
                                                      const float* __restrict__ wSum,
                                                      float* __restrict__ Out) {
    const int K = C;
    int lane = threadIdx.x & 63, wave = threadIdx.x >> 6;
    int m0 = blockIdx.y * 64 + wave * 16;
    int n0 = blockIdx.x * 64;
    int lr = lane & 15, kq = (lane >> 4) * 8;
    const _Float16* ap = A + (size_t)(m0 + lr) * K + kq;
    const _Float16* bp = BT + (size_t)(n0 + lr) * K + kq;
    f32x4 acc0 = {0.f,0.f,0.f,0.f}, acc1 = acc0, acc2 = acc0, acc3 = acc0;
    for (int k0 = 0; k0 < K; k0 += 32) {
        half8v af = *(const half8v*)(ap + k0);
        half8v b0 = *(const half8v*)(bp + k0);
        half8v b1 = *(const half8v*)(bp + (size_t)16 * K + k0);
        half8v b2 = *(const half8v*)(bp + (size_t)32 * K + k0);
        half8v b3 = *(const half8v*)(bp + (size_t)48 * K + k0);
        acc0 = __builtin_amdgcn_mfma_f32_16x16x32_f16(af, b0, acc0, 0, 0, 0);
        acc1 = __builtin_amdgcn_mfma_f32_16x16x32_f16(af, b1, acc1, 0, 0, 0);
        acc2 = __builtin_amdgcn_mfma_f32_16x16x32_f16(af, b2, acc2, 0, 0, 0);
        acc3 = __builtin_amdgcn_mfma_f32_16x16x32_f16(af, b3, acc3, 0, 0, 0);
    }
    int rb = m0 + ((lane >> 4) << 2);
    f32x4 accs[4] = {acc0, acc1, acc2, acc3};
#pragma unroll
    for (int t = 0; t < 4; ++t) {
        int col = n0 + t * 16 + lr;
        float bv = bo[col];
#pragma unroll
        for (int r = 0; r < 4; ++r) {
            int row = rb + r;
            float v = accs[t][r];
            if (row < HW) {
                v += bv;
            } else {
                float ws = wSum[row - HW];
                v = (v + bv * ws) / (ws + 1e-6f);
            }
            Out[(size_t)row * C + col] = v;
        }
    }
}

// ---------------------------------------------------------------------------
// Launch: 4 dispatches.
// ---------------------------------------------------------------------------
extern "C" void kernel_launch(void* const* d_in, const int* in_sizes, int n_in,
                              void* d_out, int out_size, void* d_ws, size_t ws_size,
                              hipStream_t stream) {
    const float* hs   = (const float*)d_in[0];
    const float* ehs  = (const float*)d_in[1];
    const float* bbox = (const float*)d_in[2];
    const float* Wq   = (const float*)d_in[3];
    const float* Wk   = (const float*)d_in[4];
    const float* Wv   = (const float*)d_in[5];
    const float* Wo   = (const float*)d_in[6];
    const float* bo   = (const float*)d_in[7];
    float* out = (float*)d_out;

    float* wPh  = (float*)d_ws;                          // 9*4096
    float* wSum = wPh + (size_t)9 * HW;                  // 4096
    _Float16* hsH  = (_Float16*)(wSum + HW);             // 8192*320
    _Float16* ehsH = hsH + (size_t)2 * HW * C;           // 770*768
    _Float16* WqT  = ehsH + (size_t)NB * L * CX;         // 320*320
    _Float16* WkvT = WqT + (size_t)C * C;                // 640*768
    _Float16* WoT  = WkvT + (size_t)KVC * CX;            // 320*320
    _Float16* Kh   = WoT + (size_t)C * C;                // 800*320
    _Float16* VTg  = Kh + (size_t)800 * C;               // 80*48*96
    _Float16* Xh   = VTg + (size_t)80 * 48 * 96;         // 8192*320

    prep_kernel<<<dim3(NPREP), 256, 0, stream>>>(bbox, hs, ehs, Wq, Wk, Wv, Wo,
                                                 wPh, wSum, hsH, ehsH, WqT, WkvT, WoT, VTg);
    gemm_kv<<<dim3(KVC / 64, (NB * L + 63) / 64), 256, 0, stream>>>(ehsH, WkvT, Kh, VTg);
    attn_mfma<<<dim3(NH * 64), 256, 0, stream>>>(hsH, WqT, Kh, VTg, wPh, Xh);
    gemm_oproj_f16<<<dim3(C / 64, (2 * HW) / 64), 256, 0, stream>>>(Xh, WoT, bo, wSum, out);
}